// Round 17
// baseline (143.064 us; speedup 1.0000x reference)
//
#include <hip/hip_runtime.h>
#include <cstdint>

#define HID 64
#define HEADS 4
#define C1 256   // HEADS*HID
#define NGRAPH 512
#define BCAP 5120       // per-bucket capacity (mean 4352, 12 sigma headroom)
#define BIN_CHUNK 4096  // edges per bin block
#define LOG2E 1.44269504f

typedef unsigned short bf16_t;
typedef __attribute__((ext_vector_type(8))) short short8v;   // 8 bf16 (4 VGPRs)
typedef __attribute__((ext_vector_type(4))) float f32x4;     // MFMA accumulator

__device__ inline bf16_t f2bf(float f) {  // round-to-nearest-even
  unsigned b = __float_as_uint(f);
  b += 0x7fffu + ((b >> 16) & 1u);
  return (bf16_t)(b >> 16);
}

// ---------------- merged constants prep: W transposes + va tables + BCNT zero ----------------

__global__ __launch_bounds__(256) void const_prep(
    const float* __restrict__ W1, const float* __restrict__ a_src,
    const float* __restrict__ a_dst, const float* __restrict__ W2,
    float* __restrict__ va, bf16_t* __restrict__ W1T, bf16_t* __restrict__ W2T,
    int* __restrict__ bcnt) {
  const int idx = blockIdx.x * 256 + threadIdx.x;  // 0..16383
  {
    const int c = idx >> 6, k = idx & 63;
    W1T[idx] = f2bf(W1[k * C1 + c]);
  }
  {
    const int c = idx >> 8, k = idx & 255;
    W2T[idx] = f2bf(W2[k * HID + c]);
  }
  if (blockIdx.x == 1) bcnt[threadIdx.x] = 0;   // replaces hipMemsetAsync dispatch
  if (blockIdx.x == 0) {
    const int t = threadIdx.x;       // t = h*64 + k
    const int h = t >> 6, k = t & 63;
    float s = 0.f, d = 0.f;
    for (int c = 0; c < 64; ++c) {
      const float w = W1[k * C1 + h * 64 + c];
      s += w * a_src[h * 64 + c];
      d += w * a_dst[h * 64 + c];
    }
    va[t] = s * LOG2E;         // pre-scaled for exp2
    va[256 + t] = d * LOG2E;
  }
}

// ---------------- prep: x -> x_bf (bf16) + scaled score tables (float4/node) ----------------

__global__ __launch_bounds__(256) void prep_kernel(
    const float* __restrict__ x, const float* __restrict__ va,
    bf16_t* __restrict__ xbf, float4* __restrict__ als, float4* __restrict__ ald,
    int Nn) {
  const int lane = threadIdx.x & 63;
  const int g = lane >> 4, sub = lane & 15;
  const int n = (blockIdx.x * 4 + (threadIdx.x >> 6)) * 4 + g;
  if (n >= Nn) return;
  const float4 xv = *reinterpret_cast<const float4*>(x + (size_t)n * HID + 4 * sub);
  ushort4 xb;
  xb.x = f2bf(xv.x); xb.y = f2bf(xv.y); xb.z = f2bf(xv.z); xb.w = f2bf(xv.w);
  *reinterpret_cast<ushort4*>(xbf + (size_t)n * HID + 4 * sub) = xb;
  float ps[HEADS], pd[HEADS];
#pragma unroll
  for (int h = 0; h < HEADS; ++h) {
    const float4 vs = *reinterpret_cast<const float4*>(va + h * 64 + 4 * sub);
    const float4 vd = *reinterpret_cast<const float4*>(va + 256 + h * 64 + 4 * sub);
    ps[h] = xv.x * vs.x + xv.y * vs.y + xv.z * vs.z + xv.w * vs.w;
    pd[h] = xv.x * vd.x + xv.y * vd.y + xv.z * vd.z + xv.w * vd.w;
  }
#pragma unroll
  for (int off = 1; off < 16; off <<= 1) {
#pragma unroll
    for (int h = 0; h < HEADS; ++h) {
      ps[h] += __shfl_xor(ps[h], off, 16);
      pd[h] += __shfl_xor(pd[h], off, 16);
    }
  }
  if (sub == 0) {
    als[n] = make_float4(ps[0], ps[1], ps[2], ps[3]);
    ald[n] = make_float4(pd[0], pd[1], pd[2], pd[3]);
  }
}

// ---------------- CSR build via LDS counting sort ----------------

__global__ __launch_bounds__(256) void bin_kernel(
    const int* __restrict__ ei, int* __restrict__ bcnt,
    unsigned* __restrict__ ebuf, int E, int Nn, int nbuck) {
  __shared__ unsigned ehold[BIN_CHUNK];
  __shared__ unsigned sorted[BIN_CHUNK];
  __shared__ unsigned char bkt[BIN_CHUNK];
  __shared__ unsigned char sbkt[BIN_CHUNK];
  __shared__ int hist[256], scanbuf[256], pref[256], ofs[256], gbase[256];
  const int t = threadIdx.x;
  const int base = blockIdx.x * BIN_CHUNK;
  const int total = E + Nn;
  const int m = min(BIN_CHUNK, total - base);
  if (m <= 0) return;

  hist[t] = 0;
  __syncthreads();
  for (int j = t; j < m; j += 256) {
    const int i = base + j;
    int s, d;
    if (i < E) { s = ei[i]; d = ei[E + i]; } else { s = d = i - E; }
    const int b = d >> 8;
    ehold[j] = ((unsigned)(d & 255) << 16) | (unsigned)s;
    bkt[j] = (unsigned char)b;
    atomicAdd(&hist[b], 1);
  }
  __syncthreads();
  const int v = hist[t];
  scanbuf[t] = v;
  __syncthreads();
  for (int off = 1; off < 256; off <<= 1) {
    const int p = (t >= off) ? scanbuf[t - off] : 0;
    __syncthreads();
    scanbuf[t] += p;
    __syncthreads();
  }
  pref[t] = scanbuf[t] - v;
  ofs[t] = 0;
  gbase[t] = (t < nbuck && v > 0) ? atomicAdd(&bcnt[t], v) : 0;
  __syncthreads();
  for (int j = t; j < m; j += 256) {
    const int b = bkt[j];
    const int r = atomicAdd(&ofs[b], 1);
    const int p = pref[b] + r;
    sorted[p] = ehold[j];
    sbkt[p] = (unsigned char)b;
  }
  __syncthreads();
  for (int j = t; j < m; j += 256) {
    const int b = sbkt[j];
    const int p = gbase[b] + (j - pref[b]);
    if (p < BCAP) ebuf[(size_t)b * BCAP + p] = sorted[j];
  }
}

__global__ __launch_bounds__(256) void csr_kernel(
    const int* __restrict__ bcnt, const unsigned* __restrict__ ebuf,
    int* __restrict__ csr, int* __restrict__ rowptr, int Nn, int nbuck) {
  __shared__ unsigned ent[BCAP];
  __shared__ unsigned short srt[BCAP];
  __shared__ int hist[256], scanbuf[256], pref[256], ofs[256];
  const int b = blockIdx.x, t = threadIdx.x;

  // parallel prefix over bucket counts
  const int bv = (t < nbuck) ? min(bcnt[t], BCAP) : 0;
  scanbuf[t] = bv;
  __syncthreads();
  for (int off = 1; off < 256; off <<= 1) {
    const int p = (t >= off) ? scanbuf[t - off] : 0;
    __syncthreads();
    scanbuf[t] += p;
    __syncthreads();
  }
  const int basev = (b > 0) ? scanbuf[b - 1] : 0;
  const int totalv = scanbuf[255];
  __syncthreads();  // scanbuf reused below

  const int m = min(bcnt[b], BCAP);
  hist[t] = 0;
  for (int j = t; j < m; j += 256) ent[j] = ebuf[(size_t)b * BCAP + j];
  __syncthreads();
  for (int j = t; j < m; j += 256) atomicAdd(&hist[ent[j] >> 16], 1);
  __syncthreads();
  const int v = hist[t];
  scanbuf[t] = v;
  __syncthreads();
  for (int off = 1; off < 256; off <<= 1) {
    const int p = (t >= off) ? scanbuf[t - off] : 0;
    __syncthreads();
    scanbuf[t] += p;
    __syncthreads();
  }
  pref[t] = scanbuf[t] - v;
  ofs[t] = 0;
  __syncthreads();
  const int d0 = b << 8;
  const int ndst = min(256, Nn - d0);
  if (t < ndst) rowptr[d0 + t] = basev + pref[t];
  if (b == 0 && t == 0) rowptr[Nn] = totalv;
  for (int j = t; j < m; j += 256) {
    const unsigned e = ent[j];
    const int dl = (int)(e >> 16);
    const int r = atomicAdd(&ofs[dl], 1);
    srt[pref[dl] + r] = (unsigned short)(e & 0xffffu);
  }
  __syncthreads();
  for (int j = t; j < m; j += 256) csr[basev + j] = (int)srt[j];
}

// ---------------- layer-1 aggregation v8 ----------------
// Phase A: one edge per lane (own csr value, float4 als gather, 4 weights, LDS).
// Invalid lanes write ZERO weights -> phase B needs no masking at all.
// Phase B: 8 edges/node/iter, 2 nodes -> 16 independent loads in flight.

#define DECL_ACC(S)                                                                     \
  float a00##S=0.f,a01##S=0.f,a02##S=0.f,a03##S=0.f,                                    \
        a10##S=0.f,a11##S=0.f,a12##S=0.f,a13##S=0.f,                                    \
        a20##S=0.f,a21##S=0.f,a22##S=0.f,a23##S=0.f,                                    \
        a30##S=0.f,a31##S=0.f,a32##S=0.f,a33##S=0.f;

#define M1_FMA(WV, HV, S) {                                                             \
    const float x0 = __uint_as_float(HV.x << 16);                                       \
    const float x1 = __uint_as_float(HV.x & 0xffff0000u);                               \
    const float x2 = __uint_as_float(HV.y << 16);                                       \
    const float x3 = __uint_as_float(HV.y & 0xffff0000u);                               \
    a00##S += WV.x * x0; a01##S += WV.x * x1; a02##S += WV.x * x2; a03##S += WV.x * x3; \
    a10##S += WV.y * x0; a11##S += WV.y * x1; a12##S += WV.y * x2; a13##S += WV.y * x3; \
    a20##S += WV.z * x0; a21##S += WV.z * x1; a22##S += WV.z * x2; a23##S += WV.z * x3; \
    a30##S += WV.w * x0; a31##S += WV.w * x1; a32##S += WV.w * x2; a33##S += WV.w * x3; \
  }

// reduce-scatter butterfly over 4 edge-slot groups; lane ends with head g's 4 feats
#define BUTTERFLY(S, O0, O1, O2, O3) {                                                  \
    float kA0 = gb0 ? a10##S : a00##S, tA0 = gb0 ? a00##S : a10##S;                     \
    float kA1 = gb0 ? a11##S : a01##S, tA1 = gb0 ? a01##S : a11##S;                     \
    float kA2 = gb0 ? a12##S : a02##S, tA2 = gb0 ? a02##S : a12##S;                     \
    float kA3 = gb0 ? a13##S : a03##S, tA3 = gb0 ? a03##S : a13##S;                     \
    float kB0 = gb0 ? a30##S : a20##S, tB0 = gb0 ? a20##S : a30##S;                     \
    float kB1 = gb0 ? a31##S : a21##S, tB1 = gb0 ? a21##S : a31##S;                     \
    float kB2 = gb0 ? a32##S : a22##S, tB2 = gb0 ? a22##S : a32##S;                     \
    float kB3 = gb0 ? a33##S : a23##S, tB3 = gb0 ? a23##S : a33##S;                     \
    kA0 += __shfl_xor(tA0, 16, 64);                                                     \
    kA1 += __shfl_xor(tA1, 16, 64);                                                     \
    kA2 += __shfl_xor(tA2, 16, 64);                                                     \
    kA3 += __shfl_xor(tA3, 16, 64);                                                     \
    kB0 += __shfl_xor(tB0, 16, 64);                                                     \
    kB1 += __shfl_xor(tB1, 16, 64);                                                     \
    kB2 += __shfl_xor(tB2, 16, 64);                                                     \
    kB3 += __shfl_xor(tB3, 16, 64);                                                     \
    float u0_ = gb1 ? kB0 : kA0, v0_ = gb1 ? kA0 : kB0;                                 \
    float u1_ = gb1 ? kB1 : kA1, v1_ = gb1 ? kA1 : kB1;                                 \
    float u2_ = gb1 ? kB2 : kA2, v2_ = gb1 ? kA2 : kB2;                                 \
    float u3_ = gb1 ? kB3 : kA3, v3_ = gb1 ? kA3 : kB3;                                 \
    O0 = u0_ + __shfl_xor(v0_, 32, 64);                                                 \
    O1 = u1_ + __shfl_xor(v1_, 32, 64);                                                 \
    O2 = u2_ + __shfl_xor(v2_, 32, 64);                                                 \
    O3 = u3_ + __shfl_xor(v3_, 32, 64);                                                 \
  }

__global__ __launch_bounds__(256) void msg1_agg(
    const int* __restrict__ rowptr, const int* __restrict__ csr,
    const float4* __restrict__ als4, const float4* __restrict__ ald4,
    const bf16_t* __restrict__ xbf, bf16_t* __restrict__ agg, int Nn) {
  __shared__ float wlds[4][2][64 * 4];   // [wave][node-slot][edge_local*4 + head], 8 KB
  const int wid = threadIdx.x >> 6;
  const int dA = blockIdx.x * 8 + wid * 2;
  if (dA >= Nn) return;
  const bool hasB = (dA + 1) < Nn;
  const int dB = hasB ? dA + 1 : dA;
  const int lane = threadIdx.x & 63;
  const int g = lane >> 4;     // edge-slot group (phase B) / output head
  const int sub = lane & 15;   // feature quad
  const int r0A = rowptr[dA], r1A = rowptr[dA + 1];
  const int r0B = rowptr[dB];
  const int r1B = hasB ? rowptr[dB + 1] : r0B;
  const float4 aldvA = ald4[dA];
  const float4 aldvB = ald4[dB];
  float* wlA = wlds[wid][0];
  float* wlB = wlds[wid][1];

  float wsA0 = 0.f, wsA1 = 0.f, wsA2 = 0.f, wsA3 = 0.f;
  float wsB0 = 0.f, wsB1 = 0.f, wsB2 = 0.f, wsB3 = 0.f;
  DECL_ACC(A)
  DECL_ACC(B)

  int cbA = r0A, cbB = r0B;
  while (cbA < r1A || cbB < r1B) {
    const int ceA = min(cbA + 64, r1A);
    const int ceB = min(cbB + 64, r1B);
    // coalesced csr loads; lane owns edge cb+lane (clamped to valid index)
    const int csrvA = csr[min(cbA + lane, r1A - 1)];
    const int csrvB = csr[min(cbB + lane, max(r1B - 1, r0B))];
    // ---- phase A: one edge per lane, all 4 head weights, zeros for invalid ----
    {
      const float4 sv = als4[csrvA];
      float s0 = sv.x + aldvA.x; s0 = fmaxf(s0, 0.2f * s0);
      float s1 = sv.y + aldvA.y; s1 = fmaxf(s1, 0.2f * s1);
      float s2 = sv.z + aldvA.z; s2 = fmaxf(s2, 0.2f * s2);
      float s3 = sv.w + aldvA.w; s3 = fmaxf(s3, 0.2f * s3);
      float w0 = exp2f(s0), w1 = exp2f(s1), w2 = exp2f(s2), w3 = exp2f(s3);
      if (cbA + lane >= ceA) { w0 = 0.f; w1 = 0.f; w2 = 0.f; w3 = 0.f; }
      wsA0 += w0; wsA1 += w1; wsA2 += w2; wsA3 += w3;
      *reinterpret_cast<float4*>(wlA + lane * 4) = make_float4(w0, w1, w2, w3);
    }
    {
      const float4 sv = als4[csrvB];
      float s0 = sv.x + aldvB.x; s0 = fmaxf(s0, 0.2f * s0);
      float s1 = sv.y + aldvB.y; s1 = fmaxf(s1, 0.2f * s1);
      float s2 = sv.z + aldvB.z; s2 = fmaxf(s2, 0.2f * s2);
      float s3 = sv.w + aldvB.w; s3 = fmaxf(s3, 0.2f * s3);
      float w0 = exp2f(s0), w1 = exp2f(s1), w2 = exp2f(s2), w3 = exp2f(s3);
      if (cbB + lane >= ceB) { w0 = 0.f; w1 = 0.f; w2 = 0.f; w3 = 0.f; }
      wsB0 += w0; wsB1 += w1; wsB2 += w2; wsB3 += w3;
      *reinterpret_cast<float4*>(wlB + lane * 4) = make_float4(w0, w1, w2, w3);
    }
    // ---- phase B: mask-free, 8 edges/node/iter (invalid slots have zero weight) ----
    const int nIter = (max(ceA - cbA, ceB - cbB) + 7) >> 3;
    int cA = cbA, cB = cbB;
    for (int k = 0; k < nIter; ++k) {
      const int iA0 = cA + g - cbA;
      const int iA1 = iA0 + 4;
      const int iB0 = cB + g - cbB;
      const int iB1 = iB0 + 4;
      const int sA0 = __shfl(csrvA, iA0, 64);
      const int sA1 = __shfl(csrvA, iA1, 64);
      const int sB0 = __shfl(csrvB, iB0, 64);
      const int sB1 = __shfl(csrvB, iB1, 64);
      const uint2 hA0 = *reinterpret_cast<const uint2*>(xbf + (size_t)sA0 * HID + 4 * sub);
      const uint2 hA1 = *reinterpret_cast<const uint2*>(xbf + (size_t)sA1 * HID + 4 * sub);
      const uint2 hB0 = *reinterpret_cast<const uint2*>(xbf + (size_t)sB0 * HID + 4 * sub);
      const uint2 hB1 = *reinterpret_cast<const uint2*>(xbf + (size_t)sB1 * HID + 4 * sub);
      const float4 wA0 = *reinterpret_cast<const float4*>(wlA + iA0 * 4);
      const float4 wA1 = *reinterpret_cast<const float4*>(wlA + iA1 * 4);
      const float4 wB0 = *reinterpret_cast<const float4*>(wlB + iB0 * 4);
      const float4 wB1 = *reinterpret_cast<const float4*>(wlB + iB1 * 4);
      M1_FMA(wA0, hA0, A)
      M1_FMA(wA1, hA1, A)
      M1_FMA(wB0, hB0, B)
      M1_FMA(wB1, hB1, B)
      cA += 8; cB += 8;
    }
    cbA += 64; cbB += 64;
  }

  // ws totals: full 64-lane butterfly per head (per-lane partials over edges)
#pragma unroll
  for (int off = 1; off < 64; off <<= 1) {
    wsA0 += __shfl_xor(wsA0, off, 64);
    wsA1 += __shfl_xor(wsA1, off, 64);
    wsA2 += __shfl_xor(wsA2, off, 64);
    wsA3 += __shfl_xor(wsA3, off, 64);
    wsB0 += __shfl_xor(wsB0, off, 64);
    wsB1 += __shfl_xor(wsB1, off, 64);
    wsB2 += __shfl_xor(wsB2, off, 64);
    wsB3 += __shfl_xor(wsB3, off, 64);
  }

  const bool gb0 = (g & 1) != 0;
  const bool gb1 = (g & 2) != 0;
  float uA0, uA1, uA2, uA3, uB0, uB1, uB2, uB3;
  BUTTERFLY(A, uA0, uA1, uA2, uA3)
  BUTTERFLY(B, uB0, uB1, uB2, uB3)

  const float wsAsel = g == 0 ? wsA0 : g == 1 ? wsA1 : g == 2 ? wsA2 : wsA3;
  const float invA = 1.f / (wsAsel + 1e-16f);
  ushort4 oA;
  oA.x = f2bf(uA0 * invA); oA.y = f2bf(uA1 * invA);
  oA.z = f2bf(uA2 * invA); oA.w = f2bf(uA3 * invA);
  *reinterpret_cast<ushort4*>(agg + ((size_t)dA * HEADS + g) * HID + 4 * sub) = oA;
  if (hasB) {
    const float wsBsel = g == 0 ? wsB0 : g == 1 ? wsB1 : g == 2 ? wsB2 : wsB3;
    const float invB = 1.f / (wsBsel + 1e-16f);
    ushort4 oB;
    oB.x = f2bf(uB0 * invB); oB.y = f2bf(uB1 * invB);
    oB.z = f2bf(uB2 * invB); oB.w = f2bf(uB3 * invB);
    *reinterpret_cast<ushort4*>(agg + ((size_t)dB * HEADS + g) * HID + 4 * sub) = oB;
  }
}

// ---------------- fused dense chain on MFMA: 16 nodes/block, 4 waves ----------------

__global__ __launch_bounds__(256) void gemm12_mfma(
    const bf16_t* __restrict__ agg, const bf16_t* __restrict__ W1T,
    const float* __restrict__ b1, const bf16_t* __restrict__ W2T,
    const float* __restrict__ a2s, const float* __restrict__ a2d,
    bf16_t* __restrict__ h2, float* __restrict__ als2, float* __restrict__ ald2,
    int Nn) {
  __shared__ bf16_t x2s[16][264];     // x2 tile [node][col], 528B row stride
  __shared__ float pbuf_s[4][16], pbuf_d[4][16];
  const int w = threadIdx.x >> 6;     // wave id = head (ph1) / col quartile (ph2)
  const int l = threadIdx.x & 63;
  const int n0 = blockIdx.x * 16;
  if (n0 >= Nn) return;
  const int r16 = l & 15, g = l >> 4;

  const f32x4 zz = {0.f, 0.f, 0.f, 0.f};
  f32x4 acc1[4];
#pragma unroll
  for (int ct = 0; ct < 4; ++ct) acc1[ct] = zz;

  // ---- phase 1: head w, K=64 (2 MFMA K-steps x 4 col tiles) ----
  const bf16_t* arow = agg + (size_t)(n0 + r16) * C1 + w * 64;
#pragma unroll
  for (int ks = 0; ks < 2; ++ks) {
    const short8v bfrag = *reinterpret_cast<const short8v*>(arow + ks * 32 + g * 8);
#pragma unroll
    for (int ct = 0; ct < 4; ++ct) {
      const short8v afrag = *reinterpret_cast<const short8v*>(
          W1T + (size_t)(w * 64 + ct * 16 + r16) * 64 + ks * 32 + g * 8);
      acc1[ct] = __builtin_amdgcn_mfma_f32_16x16x32_bf16(afrag, bfrag, acc1[ct], 0, 0, 0);
    }
  }

  // bias + ELU (cheap exp-1) + bf16 pack -> LDS
#pragma unroll
  for (int ct = 0; ct < 4; ++ct) {
    const float4 bv = *reinterpret_cast<const float4*>(b1 + w * 64 + ct * 16 + g * 4);
    float v0 = acc1[ct][0] + bv.x;
    float v1 = acc1[ct][1] + bv.y;
    float v2 = acc1[ct][2] + bv.z;
    float v3 = acc1[ct][3] + bv.w;
    v0 = v0 > 0.f ? v0 : __expf(v0) - 1.f;
    v1 = v1 > 0.f ? v1 : __expf(v1) - 1.f;
    v2 = v2 > 0.f ? v2 : __expf(v2) - 1.f;
    v3 = v3 > 0.f ? v3 : __expf(v3) - 1.f;
    uint2 pk;
    pk.x = (unsigned)f2bf(v0) | ((unsigned)f2bf(v1) << 16);
    pk.y = (unsigned)f2bf(v2) | ((unsigned)f2bf(v3) << 16);
    *reinterpret_cast<uint2*>(&x2s[r16][w * 64 + ct * 16 + g * 4]) = pk;
  }
  __syncthreads();

  // ---- phase 2: h2 col block w*16..w*16+15, K=256 (8 MFMA K-steps) ----
  f32x4 acc2 = zz;
#pragma unroll
  for (int s2 = 0; s2 < 8; ++s2) {
    const short8v bfrag = *reinterpret_cast<const short8v*>(&x2s[r16][s2 * 32 + g * 8]);
    const short8v afrag = *reinterpret_cast<const short8v*>(
        W2T + (size_t)(w * 16 + r16) * 256 + s2 * 32 + g * 8);
    acc2 = __builtin_amdgcn_mfma_f32_16x16x32_bf16(afrag, bfrag, acc2, 0, 0, 0);
  }

  // epilogue: h2 bf16 write + score partials
  const float4 avs = *reinterpret_cast<const float4*>(a2s + w * 16 + g * 4);
  const float4 avd = *reinterpret_cast<const float4*>(a2d + w * 16 + g * 4);
  float ps = acc2[0] * avs.x + acc2[1] * avs.y + acc2[2] * avs.z + acc2[3] * avs.w;
  float pd = acc2[0] * avd.x + acc2[1] * avd.y + acc2[2] * avd.z + acc2[3] * avd.w;
  ushort4 hb;
  hb.x = f2bf(acc2[0]); hb.y = f2bf(acc2[1]);
  hb.z = f2bf(acc2[2]); hb.w = f2bf(acc2[3]);
  *reinterpret_cast<ushort4*>(h2 + (size_t)(n0 + r16) * HID + w * 16 + g * 4) = hb;
  ps += __shfl_xor(ps, 16, 64);
  ps += __shfl_xor(ps, 32, 64);
  pd += __shfl_xor(pd, 16, 64);
  pd += __shfl_xor(pd, 32, 64);
  if (g == 0) { pbuf_s[w][r16] = ps; pbuf_d[w][r16] = pd; }
  __syncthreads();
  if (w == 0 && g == 0) {
    const float pst = pbuf_s[0][r16] + pbuf_s[1][r16] + pbuf_s[2][r16] + pbuf_s[3][r16];
    const float pdt = pbuf_d[0][r16] + pbuf_d[1][r16] + pbuf_d[2][r16] + pbuf_d[3][r16];
    als2[n0 + r16] = pst * LOG2E;
    ald2[n0 + r16] = pdt * LOG2E;
  }
}

// ---------------- layer-2 aggregation (exp2, max-leaky) ----------------

__global__ __launch_bounds__(256) void msg2_fused(
    const int* __restrict__ rowptr, const int* __restrict__ csr,
    const float* __restrict__ als2, const float* __restrict__ ald2,
    const bf16_t* __restrict__ h2, const float* __restrict__ b2,
    float* __restrict__ out, int Nn) {
  const int lane = threadIdx.x & 63;
  const int g = lane >> 4, sub = lane & 15;
  const int d = (blockIdx.x * 4 + (threadIdx.x >> 6)) * 4 + g;
  if (d >= Nn) return;
  const int r0 = rowptr[d], r1 = rowptr[d + 1];
  const float aldd = ald2[d];
  float wsum = 0.f;
  float a0 = 0.f, a1 = 0.f, a2 = 0.f, a3 = 0.f;

#define M2_EDGE(EI) {                                                                \
    const int s_ = csr[EI];                                                          \
    float sc_ = als2[s_] + aldd;                                                     \
    sc_ = fmaxf(sc_, 0.2f * sc_);                                                    \
    const float w_ = exp2f(sc_);                                                     \
    wsum += w_;                                                                      \
    const uint2 hv_ = *reinterpret_cast<const uint2*>(h2 + (size_t)s_ * HID + 4 * sub); \
    a0 += w_ * __uint_as_float(hv_.x << 16);                                         \
    a1 += w_ * __uint_as_float(hv_.x & 0xffff0000u);                                 \
    a2 += w_ * __uint_as_float(hv_.y << 16);                                         \
    a3 += w_ * __uint_as_float(hv_.y & 0xffff0000u);                                 \
  }

  int e = r0;
  for (; e + 4 <= r1; e += 4) { M2_EDGE(e) M2_EDGE(e + 1) M2_EDGE(e + 2) M2_EDGE(e + 3) }
  for (; e < r1; ++e) { M2_EDGE(e) }

  const float inv = 1.f / (wsum + 1e-16f);
  const float4 bb = *reinterpret_cast<const float4*>(b2 + 4 * sub);
  float4 o;
  o.x = a0 * inv + bb.x;
  o.y = a1 * inv + bb.y;
  o.z = a2 * inv + bb.z;
  o.w = a3 * inv + bb.w;
  *reinterpret_cast<float4*>(out + (size_t)d * HID + 4 * sub) = o;
}

// ---------------- fused pool + classifier (4 waves/graph, unrolled MLP) ----------------

__device__ inline int lbound(const int* __restrict__ a, int n, int v) {
  int lo = 0, hi = n;
  while (lo < hi) { int m = (lo + hi) >> 1; if (a[m] < v) lo = m + 1; else hi = m; }
  return lo;
}

__global__ __launch_bounds__(256) void pool_cls_kernel(
    const float* __restrict__ out2, const int* __restrict__ batch,
    const float* __restrict__ Wc, const float* __restrict__ bc,
    float* __restrict__ out, int Nn, int C) {
  __shared__ float part[4][HID];
  __shared__ float es[HID];
  const int g = blockIdx.x;
  const int w = threadIdx.x >> 6;      // wave id: node-range slice
  const int t = threadIdx.x & 63;      // feature
  const int lo = lbound(batch, Nn, g);
  const int hi = lbound(batch, Nn, g + 1);
  float acc0 = 0.f, acc1 = 0.f, acc2 = 0.f, acc3 = 0.f;
  int n = lo + w;
  for (; n + 12 < hi; n += 16) {
    acc0 += out2[(size_t)(n) * HID + t];
    acc1 += out2[(size_t)(n + 4) * HID + t];
    acc2 += out2[(size_t)(n + 8) * HID + t];
    acc3 += out2[(size_t)(n + 12) * HID + t];
  }
  for (; n < hi; n += 4) acc0 += out2[(size_t)n * HID + t];
  part[w][t] = (acc0 + acc1) + (acc2 + acc3);
  __syncthreads();
  if (w == 0) {
    const int cnt = hi - lo;
    const float cf = (float)(cnt > 1 ? cnt : 1);
    es[t] = (part[0][t] + part[1][t] + part[2][t] + part[3][t]) / cf;
  }
  __syncthreads();
  for (int c = threadIdx.x; c < C; c += 256) {
    float a = bc[c];
#pragma unroll
    for (int d = 0; d < HID; ++d) a += es[d] * Wc[d * C + c];
    out[g * C + c] = a;
  }
}

extern "C" void kernel_launch(void* const* d_in, const int* in_sizes, int n_in,
                              void* d_out, int out_size, void* d_ws, size_t ws_size,
                              hipStream_t stream) {
  const float* x      = (const float*)d_in[0];
  const float* W1     = (const float*)d_in[1];
  const float* a_src1 = (const float*)d_in[2];
  const float* a_dst1 = (const float*)d_in[3];
  const float* b1     = (const float*)d_in[4];
  const float* W2     = (const float*)d_in[5];
  const float* a_src2 = (const float*)d_in[6];
  const float* a_dst2 = (const float*)d_in[7];
  const float* b2     = (const float*)d_in[8];
  const float* Wc     = (const float*)d_in[9];
  const float* bc     = (const float*)d_in[10];
  const int*   ei     = (const int*)d_in[11];
  const int*   batch  = (const int*)d_in[12];

  const int N = in_sizes[0] / HID;   // 50000
  const int E = in_sizes[11] / 2;    // 800000
  const int C = in_sizes[10];        // 120
  const int Etot = E + N;
  const int nbuck = (N + 255) >> 8;  // 196

  // workspace layout (all regions 16B-aligned)
  bf16_t* AGG = (bf16_t*)d_ws;                          // N*256 bf16; OUT2 f32 overlay later
  bf16_t* XBF = AGG + (size_t)N * C1;                   // N*64 bf16 -> h2 overlay
  float4* ALS1 = (float4*)(XBF + (size_t)N * HID);      // N float4 (scaled)
  float4* ALD1 = ALS1 + N;                              // N float4
  float* ALS2 = (float*)(ALD1 + N);                     // N f32 (scaled)
  float* ALD2 = ALS2 + N;                               // N f32
  int* ROWP   = (int*)(ALD2 + N);                       // N+4 (padded)
  int* BCNT   = ROWP + (N + 4);                         // 256
  int* CSR    = BCNT + 256;                             // Etot
  unsigned* EBUF = (unsigned*)(CSR + Etot);             // 256*BCAP
  float* VA   = (float*)(EBUF + 256 * BCAP);            // 512
  bf16_t* W1T = (bf16_t*)(VA + 512);                    // 16384 bf16
  bf16_t* W2T = W1T + 16384;                            // 16384 bf16

  bf16_t* H2B = XBF;                     // overlay (x_bf dead after msg1_agg)
  float* OUT2 = (float*)AGG;             // overlay (agg dead after gemm12_mfma)

  // ---- constants + BCNT zero (replaces memset dispatch) ----
  const_prep<<<64, 256, 0, stream>>>(W1, a_src1, a_dst1, W2, VA, W1T, W2T, BCNT);

  // ---- CSR build (bucket counting sort, all scatter in LDS) ----
  bin_kernel<<<(Etot + BIN_CHUNK - 1) / BIN_CHUNK, 256, 0, stream>>>(ei, BCNT, EBUF, E, N, nbuck);
  csr_kernel<<<nbuck, 256, 0, stream>>>(BCNT, EBUF, CSR, ROWP, N, nbuck);

  // ---- layer 1 ----
  prep_kernel<<<(N + 15) / 16, 256, 0, stream>>>(x, VA, XBF, ALS1, ALD1, N);
  msg1_agg<<<(N + 7) / 8, 256, 0, stream>>>(ROWP, CSR, ALS1, ALD1, XBF, AGG, N);

  // ---- fused dense chain on MFMA: agg -> x2 (LDS) -> h2, score scalars ----
  gemm12_mfma<<<(N + 15) / 16, 256, 0, stream>>>(AGG, W1T, b1, W2T, a_src2, a_dst2,
                                                 H2B, ALS2, ALD2, N);

  // ---- layer 2 aggregation ----
  msg2_fused<<<(N + 15) / 16, 256, 0, stream>>>(ROWP, CSR, ALS2, ALD2, H2B, b2, OUT2, N);

  // ---- pool + classifier ----
  pool_cls_kernel<<<NGRAPH, 256, 0, stream>>>(OUT2, batch, Wc, bc, (float*)d_out, N, C);
}

// Round 18
// 136.682 us; speedup vs baseline: 1.0467x; 1.0467x over previous
//
#include <hip/hip_runtime.h>
#include <cstdint>

#define HID 64
#define HEADS 4
#define C1 256   // HEADS*HID
#define NGRAPH 512
#define BCAP 5120       // per-bucket capacity (mean 4352, 12 sigma headroom)
#define BIN_CHUNK 4096  // edges per bin block
#define LOG2E 1.44269504f

typedef unsigned short bf16_t;
typedef __attribute__((ext_vector_type(8))) short short8v;   // 8 bf16 (4 VGPRs)
typedef __attribute__((ext_vector_type(4))) float f32x4;     // MFMA accumulator

__device__ inline bf16_t f2bf(float f) {  // round-to-nearest-even
  unsigned b = __float_as_uint(f);
  b += 0x7fffu + ((b >> 16) & 1u);
  return (bf16_t)(b >> 16);
}

// ---------------- merged constants prep: W transposes + va tables + BCNT zero ----------------

__global__ __launch_bounds__(256) void const_prep(
    const float* __restrict__ W1, const float* __restrict__ a_src,
    const float* __restrict__ a_dst, const float* __restrict__ W2,
    float* __restrict__ va, bf16_t* __restrict__ W1T, bf16_t* __restrict__ W2T,
    int* __restrict__ bcnt) {
  const int idx = blockIdx.x * 256 + threadIdx.x;  // 0..16383
  {
    const int c = idx >> 6, k = idx & 63;
    W1T[idx] = f2bf(W1[k * C1 + c]);
  }
  {
    const int c = idx >> 8, k = idx & 255;
    W2T[idx] = f2bf(W2[k * HID + c]);
  }
  if (blockIdx.x == 1) bcnt[threadIdx.x] = 0;   // replaces hipMemsetAsync dispatch
  if (blockIdx.x == 0) {
    const int t = threadIdx.x;       // t = h*64 + k
    const int h = t >> 6, k = t & 63;
    float s = 0.f, d = 0.f;
    for (int c = 0; c < 64; ++c) {
      const float w = W1[k * C1 + h * 64 + c];
      s += w * a_src[h * 64 + c];
      d += w * a_dst[h * 64 + c];
    }
    va[t] = s * LOG2E;         // pre-scaled for exp2
    va[256 + t] = d * LOG2E;
  }
}

// ---------------- prep: x -> x_bf (bf16) + scaled score tables (float4/node) ----------------

__global__ __launch_bounds__(256) void prep_kernel(
    const float* __restrict__ x, const float* __restrict__ va,
    bf16_t* __restrict__ xbf, float4* __restrict__ als, float4* __restrict__ ald,
    int Nn) {
  const int lane = threadIdx.x & 63;
  const int g = lane >> 4, sub = lane & 15;
  const int n = (blockIdx.x * 4 + (threadIdx.x >> 6)) * 4 + g;
  if (n >= Nn) return;
  const float4 xv = *reinterpret_cast<const float4*>(x + (size_t)n * HID + 4 * sub);
  ushort4 xb;
  xb.x = f2bf(xv.x); xb.y = f2bf(xv.y); xb.z = f2bf(xv.z); xb.w = f2bf(xv.w);
  *reinterpret_cast<ushort4*>(xbf + (size_t)n * HID + 4 * sub) = xb;
  float ps[HEADS], pd[HEADS];
#pragma unroll
  for (int h = 0; h < HEADS; ++h) {
    const float4 vs = *reinterpret_cast<const float4*>(va + h * 64 + 4 * sub);
    const float4 vd = *reinterpret_cast<const float4*>(va + 256 + h * 64 + 4 * sub);
    ps[h] = xv.x * vs.x + xv.y * vs.y + xv.z * vs.z + xv.w * vs.w;
    pd[h] = xv.x * vd.x + xv.y * vd.y + xv.z * vd.z + xv.w * vd.w;
  }
#pragma unroll
  for (int off = 1; off < 16; off <<= 1) {
#pragma unroll
    for (int h = 0; h < HEADS; ++h) {
      ps[h] += __shfl_xor(ps[h], off, 16);
      pd[h] += __shfl_xor(pd[h], off, 16);
    }
  }
  if (sub == 0) {
    als[n] = make_float4(ps[0], ps[1], ps[2], ps[3]);
    ald[n] = make_float4(pd[0], pd[1], pd[2], pd[3]);
  }
}

// ---------------- CSR build via LDS counting sort ----------------

__global__ __launch_bounds__(256) void bin_kernel(
    const int* __restrict__ ei, int* __restrict__ bcnt,
    unsigned* __restrict__ ebuf, int E, int Nn, int nbuck) {
  __shared__ unsigned ehold[BIN_CHUNK];
  __shared__ unsigned sorted[BIN_CHUNK];
  __shared__ unsigned char bkt[BIN_CHUNK];
  __shared__ unsigned char sbkt[BIN_CHUNK];
  __shared__ int hist[256], scanbuf[256], pref[256], ofs[256], gbase[256];
  const int t = threadIdx.x;
  const int base = blockIdx.x * BIN_CHUNK;
  const int total = E + Nn;
  const int m = min(BIN_CHUNK, total - base);
  if (m <= 0) return;

  hist[t] = 0;
  __syncthreads();
  for (int j = t; j < m; j += 256) {
    const int i = base + j;
    int s, d;
    if (i < E) { s = ei[i]; d = ei[E + i]; } else { s = d = i - E; }
    const int b = d >> 8;
    ehold[j] = ((unsigned)(d & 255) << 16) | (unsigned)s;
    bkt[j] = (unsigned char)b;
    atomicAdd(&hist[b], 1);
  }
  __syncthreads();
  const int v = hist[t];
  scanbuf[t] = v;
  __syncthreads();
  for (int off = 1; off < 256; off <<= 1) {
    const int p = (t >= off) ? scanbuf[t - off] : 0;
    __syncthreads();
    scanbuf[t] += p;
    __syncthreads();
  }
  pref[t] = scanbuf[t] - v;
  ofs[t] = 0;
  gbase[t] = (t < nbuck && v > 0) ? atomicAdd(&bcnt[t], v) : 0;
  __syncthreads();
  for (int j = t; j < m; j += 256) {
    const int b = bkt[j];
    const int r = atomicAdd(&ofs[b], 1);
    const int p = pref[b] + r;
    sorted[p] = ehold[j];
    sbkt[p] = (unsigned char)b;
  }
  __syncthreads();
  for (int j = t; j < m; j += 256) {
    const int b = sbkt[j];
    const int p = gbase[b] + (j - pref[b]);
    if (p < BCAP) ebuf[(size_t)b * BCAP + p] = sorted[j];
  }
}

__global__ __launch_bounds__(256) void csr_kernel(
    const int* __restrict__ bcnt, const unsigned* __restrict__ ebuf,
    int* __restrict__ csr, int* __restrict__ rowptr, int Nn, int nbuck) {
  __shared__ unsigned ent[BCAP];
  __shared__ unsigned short srt[BCAP];
  __shared__ int hist[256], scanbuf[256], pref[256], ofs[256];
  const int b = blockIdx.x, t = threadIdx.x;

  // parallel prefix over bucket counts
  const int bv = (t < nbuck) ? min(bcnt[t], BCAP) : 0;
  scanbuf[t] = bv;
  __syncthreads();
  for (int off = 1; off < 256; off <<= 1) {
    const int p = (t >= off) ? scanbuf[t - off] : 0;
    __syncthreads();
    scanbuf[t] += p;
    __syncthreads();
  }
  const int basev = (b > 0) ? scanbuf[b - 1] : 0;
  const int totalv = scanbuf[255];
  __syncthreads();  // scanbuf reused below

  const int m = min(bcnt[b], BCAP);
  hist[t] = 0;
  for (int j = t; j < m; j += 256) ent[j] = ebuf[(size_t)b * BCAP + j];
  __syncthreads();
  for (int j = t; j < m; j += 256) atomicAdd(&hist[ent[j] >> 16], 1);
  __syncthreads();
  const int v = hist[t];
  scanbuf[t] = v;
  __syncthreads();
  for (int off = 1; off < 256; off <<= 1) {
    const int p = (t >= off) ? scanbuf[t - off] : 0;
    __syncthreads();
    scanbuf[t] += p;
    __syncthreads();
  }
  pref[t] = scanbuf[t] - v;
  ofs[t] = 0;
  __syncthreads();
  const int d0 = b << 8;
  const int ndst = min(256, Nn - d0);
  if (t < ndst) rowptr[d0 + t] = basev + pref[t];
  if (b == 0 && t == 0) rowptr[Nn] = totalv;
  for (int j = t; j < m; j += 256) {
    const unsigned e = ent[j];
    const int dl = (int)(e >> 16);
    const int r = atomicAdd(&ofs[dl], 1);
    srt[pref[dl] + r] = (unsigned short)(e & 0xffffu);
  }
  __syncthreads();
  for (int j = t; j < m; j += 256) csr[basev + j] = (int)srt[j];
}

// ---------------- layer-1 aggregation v9: group-per-node, 16B gathers, reg weights ----------------
// 4 nodes/wave; 16 lanes per node: epar = edge parity, sub8 = feature octet.
// Weight phase: lane l16 owns edge cb+l16 (coalesced csr, 16B als4 gather, 4 weights in regs).
// Gather: 2 edges/step via epar halves; weights via 4 in-group shfls; 16B xbf loads.
// Accumulators acc[4][8] are final per lane: epilogue = one xor-8 merge + ws reduce.

__global__ __launch_bounds__(256) void msg1_agg(
    const int* __restrict__ rowptr, const int* __restrict__ csr,
    const float4* __restrict__ als4, const float4* __restrict__ ald4,
    const bf16_t* __restrict__ xbf, bf16_t* __restrict__ agg, int Nn) {
  const int wid = threadIdx.x >> 6;
  const int lane = threadIdx.x & 63;
  const int l16 = lane & 15;
  const int epar = l16 >> 3;       // 0/1: which edge of the pair
  const int sub8 = l16 & 7;        // feature octet: feats 8*sub8..+7
  int d = (blockIdx.x * 4 + wid) * 4 + (lane >> 4);
  const bool dvalid = d < Nn;
  if (!dvalid) d = Nn - 1;
  const int r0 = rowptr[d], r1 = rowptr[d + 1];
  const float4 aldv = ald4[d];

  float acc[4][8];
#pragma unroll
  for (int h = 0; h < 4; ++h)
#pragma unroll
    for (int f = 0; f < 8; ++f) acc[h][f] = 0.f;
  float ws0 = 0.f, ws1 = 0.f, ws2 = 0.f, ws3 = 0.f;

  const int base = (lane & 48) + epar;   // group base for shfl index
  int cb = r0;
  int maxrem = r1 - cb;
  maxrem = max(maxrem, __shfl_xor(maxrem, 16, 64));
  maxrem = max(maxrem, __shfl_xor(maxrem, 32, 64));
  while (maxrem > 0) {
    // ---- weight phase: lane l16 owns edge cb+l16; all 4 head weights in regs ----
    const int eown = cb + l16;
    const int s_ = csr[min(eown, r1 - 1)];
    const float4 sv = als4[s_];
    float t0 = sv.x + aldv.x; t0 = fmaxf(t0, 0.2f * t0);
    float t1 = sv.y + aldv.y; t1 = fmaxf(t1, 0.2f * t1);
    float t2 = sv.z + aldv.z; t2 = fmaxf(t2, 0.2f * t2);
    float t3 = sv.w + aldv.w; t3 = fmaxf(t3, 0.2f * t3);
    float w0 = exp2f(t0), w1 = exp2f(t1), w2 = exp2f(t2), w3 = exp2f(t3);
    if (eown >= r1) { w0 = 0.f; w1 = 0.f; w2 = 0.f; w3 = 0.f; }
    ws0 += w0; ws1 += w1; ws2 += w2; ws3 += w3;
    // ---- gather: 2 edges/step (epar halves), mask-free (zero weights) ----
    const int nstep = (min(16, maxrem) + 1) >> 1;
    for (int t = 0; t < nstep; ++t) {
      const int idx = base + 2 * t;
      const float wj0 = __shfl(w0, idx, 64);
      const float wj1 = __shfl(w1, idx, 64);
      const float wj2 = __shfl(w2, idx, 64);
      const float wj3 = __shfl(w3, idx, 64);
      const int sj = __shfl(s_, idx, 64);
      const uint4 hv = *reinterpret_cast<const uint4*>(xbf + (size_t)sj * HID + 8 * sub8);
      float xv[8];
      xv[0] = __uint_as_float(hv.x << 16);
      xv[1] = __uint_as_float(hv.x & 0xffff0000u);
      xv[2] = __uint_as_float(hv.y << 16);
      xv[3] = __uint_as_float(hv.y & 0xffff0000u);
      xv[4] = __uint_as_float(hv.z << 16);
      xv[5] = __uint_as_float(hv.z & 0xffff0000u);
      xv[6] = __uint_as_float(hv.w << 16);
      xv[7] = __uint_as_float(hv.w & 0xffff0000u);
#pragma unroll
      for (int f = 0; f < 8; ++f) {
        acc[0][f] += wj0 * xv[f];
        acc[1][f] += wj1 * xv[f];
        acc[2][f] += wj2 * xv[f];
        acc[3][f] += wj3 * xv[f];
      }
    }
    cb += 16;
    maxrem = r1 - cb;
    maxrem = max(maxrem, __shfl_xor(maxrem, 16, 64));
    maxrem = max(maxrem, __shfl_xor(maxrem, 32, 64));
  }

  // ws: reduce over the 16 lanes of the group (each owned distinct edges)
#pragma unroll
  for (int off = 1; off < 16; off <<= 1) {
    ws0 += __shfl_xor(ws0, off, 64);
    ws1 += __shfl_xor(ws1, off, 64);
    ws2 += __shfl_xor(ws2, off, 64);
    ws3 += __shfl_xor(ws3, off, 64);
  }
  // acc: merge the two epar halves (both end with the total)
#pragma unroll
  for (int h = 0; h < 4; ++h)
#pragma unroll
    for (int f = 0; f < 8; ++f) acc[h][f] += __shfl_xor(acc[h][f], 8, 64);

  if (dvalid) {
    const float i0 = 1.f / (ws0 + 1e-16f);
    const float i1 = 1.f / (ws1 + 1e-16f);
    const float i2 = 1.f / (ws2 + 1e-16f);
    const float i3 = 1.f / (ws3 + 1e-16f);
    // epar 0 writes heads 0,1 ; epar 1 writes heads 2,3 (static reg indices)
    float o0[8], o1[8];
#pragma unroll
    for (int f = 0; f < 8; ++f) {
      o0[f] = epar ? acc[2][f] : acc[0][f];
      o1[f] = epar ? acc[3][f] : acc[1][f];
    }
    const float iv0 = epar ? i2 : i0;
    const float iv1 = epar ? i3 : i1;
    const int h0 = epar * 2;
    uint4 p0, p1;
    p0.x = (unsigned)f2bf(o0[0] * iv0) | ((unsigned)f2bf(o0[1] * iv0) << 16);
    p0.y = (unsigned)f2bf(o0[2] * iv0) | ((unsigned)f2bf(o0[3] * iv0) << 16);
    p0.z = (unsigned)f2bf(o0[4] * iv0) | ((unsigned)f2bf(o0[5] * iv0) << 16);
    p0.w = (unsigned)f2bf(o0[6] * iv0) | ((unsigned)f2bf(o0[7] * iv0) << 16);
    p1.x = (unsigned)f2bf(o1[0] * iv1) | ((unsigned)f2bf(o1[1] * iv1) << 16);
    p1.y = (unsigned)f2bf(o1[2] * iv1) | ((unsigned)f2bf(o1[3] * iv1) << 16);
    p1.z = (unsigned)f2bf(o1[4] * iv1) | ((unsigned)f2bf(o1[5] * iv1) << 16);
    p1.w = (unsigned)f2bf(o1[6] * iv1) | ((unsigned)f2bf(o1[7] * iv1) << 16);
    *reinterpret_cast<uint4*>(agg + ((size_t)d * HEADS + h0) * HID + 8 * sub8) = p0;
    *reinterpret_cast<uint4*>(agg + ((size_t)d * HEADS + h0 + 1) * HID + 8 * sub8) = p1;
  }
}

// ---------------- fused dense chain on MFMA: 16 nodes/block, 4 waves ----------------

__global__ __launch_bounds__(256) void gemm12_mfma(
    const bf16_t* __restrict__ agg, const bf16_t* __restrict__ W1T,
    const float* __restrict__ b1, const bf16_t* __restrict__ W2T,
    const float* __restrict__ a2s, const float* __restrict__ a2d,
    bf16_t* __restrict__ h2, float* __restrict__ als2, float* __restrict__ ald2,
    int Nn) {
  __shared__ bf16_t x2s[16][264];     // x2 tile [node][col], 528B row stride
  __shared__ float pbuf_s[4][16], pbuf_d[4][16];
  const int w = threadIdx.x >> 6;     // wave id = head (ph1) / col quartile (ph2)
  const int l = threadIdx.x & 63;
  const int n0 = blockIdx.x * 16;
  if (n0 >= Nn) return;
  const int r16 = l & 15, g = l >> 4;

  const f32x4 zz = {0.f, 0.f, 0.f, 0.f};
  f32x4 acc1[4];
#pragma unroll
  for (int ct = 0; ct < 4; ++ct) acc1[ct] = zz;

  // ---- phase 1: head w, K=64 (2 MFMA K-steps x 4 col tiles) ----
  const bf16_t* arow = agg + (size_t)(n0 + r16) * C1 + w * 64;
#pragma unroll
  for (int ks = 0; ks < 2; ++ks) {
    const short8v bfrag = *reinterpret_cast<const short8v*>(arow + ks * 32 + g * 8);
#pragma unroll
    for (int ct = 0; ct < 4; ++ct) {
      const short8v afrag = *reinterpret_cast<const short8v*>(
          W1T + (size_t)(w * 64 + ct * 16 + r16) * 64 + ks * 32 + g * 8);
      acc1[ct] = __builtin_amdgcn_mfma_f32_16x16x32_bf16(afrag, bfrag, acc1[ct], 0, 0, 0);
    }
  }

  // bias + ELU (cheap exp-1) + bf16 pack -> LDS
#pragma unroll
  for (int ct = 0; ct < 4; ++ct) {
    const float4 bv = *reinterpret_cast<const float4*>(b1 + w * 64 + ct * 16 + g * 4);
    float v0 = acc1[ct][0] + bv.x;
    float v1 = acc1[ct][1] + bv.y;
    float v2 = acc1[ct][2] + bv.z;
    float v3 = acc1[ct][3] + bv.w;
    v0 = v0 > 0.f ? v0 : __expf(v0) - 1.f;
    v1 = v1 > 0.f ? v1 : __expf(v1) - 1.f;
    v2 = v2 > 0.f ? v2 : __expf(v2) - 1.f;
    v3 = v3 > 0.f ? v3 : __expf(v3) - 1.f;
    uint2 pk;
    pk.x = (unsigned)f2bf(v0) | ((unsigned)f2bf(v1) << 16);
    pk.y = (unsigned)f2bf(v2) | ((unsigned)f2bf(v3) << 16);
    *reinterpret_cast<uint2*>(&x2s[r16][w * 64 + ct * 16 + g * 4]) = pk;
  }
  __syncthreads();

  // ---- phase 2: h2 col block w*16..w*16+15, K=256 (8 MFMA K-steps) ----
  f32x4 acc2 = zz;
#pragma unroll
  for (int s2 = 0; s2 < 8; ++s2) {
    const short8v bfrag = *reinterpret_cast<const short8v*>(&x2s[r16][s2 * 32 + g * 8]);
    const short8v afrag = *reinterpret_cast<const short8v*>(
        W2T + (size_t)(w * 16 + r16) * 256 + s2 * 32 + g * 8);
    acc2 = __builtin_amdgcn_mfma_f32_16x16x32_bf16(afrag, bfrag, acc2, 0, 0, 0);
  }

  // epilogue: h2 bf16 write + score partials
  const float4 avs = *reinterpret_cast<const float4*>(a2s + w * 16 + g * 4);
  const float4 avd = *reinterpret_cast<const float4*>(a2d + w * 16 + g * 4);
  float ps = acc2[0] * avs.x + acc2[1] * avs.y + acc2[2] * avs.z + acc2[3] * avs.w;
  float pd = acc2[0] * avd.x + acc2[1] * avd.y + acc2[2] * avd.z + acc2[3] * avd.w;
  ushort4 hb;
  hb.x = f2bf(acc2[0]); hb.y = f2bf(acc2[1]);
  hb.z = f2bf(acc2[2]); hb.w = f2bf(acc2[3]);
  *reinterpret_cast<ushort4*>(h2 + (size_t)(n0 + r16) * HID + w * 16 + g * 4) = hb;
  ps += __shfl_xor(ps, 16, 64);
  ps += __shfl_xor(ps, 32, 64);
  pd += __shfl_xor(pd, 16, 64);
  pd += __shfl_xor(pd, 32, 64);
  if (g == 0) { pbuf_s[w][r16] = ps; pbuf_d[w][r16] = pd; }
  __syncthreads();
  if (w == 0 && g == 0) {
    const float pst = pbuf_s[0][r16] + pbuf_s[1][r16] + pbuf_s[2][r16] + pbuf_s[3][r16];
    const float pdt = pbuf_d[0][r16] + pbuf_d[1][r16] + pbuf_d[2][r16] + pbuf_d[3][r16];
    als2[n0 + r16] = pst * LOG2E;
    ald2[n0 + r16] = pdt * LOG2E;
  }
}

// ---------------- layer-2 aggregation (exp2, max-leaky) ----------------

__global__ __launch_bounds__(256) void msg2_fused(
    const int* __restrict__ rowptr, const int* __restrict__ csr,
    const float* __restrict__ als2, const float* __restrict__ ald2,
    const bf16_t* __restrict__ h2, const float* __restrict__ b2,
    float* __restrict__ out, int Nn) {
  const int lane = threadIdx.x & 63;
  const int g = lane >> 4, sub = lane & 15;
  const int d = (blockIdx.x * 4 + (threadIdx.x >> 6)) * 4 + g;
  if (d >= Nn) return;
  const int r0 = rowptr[d], r1 = rowptr[d + 1];
  const float aldd = ald2[d];
  float wsum = 0.f;
  float a0 = 0.f, a1 = 0.f, a2 = 0.f, a3 = 0.f;

#define M2_EDGE(EI) {                                                                \
    const int s_ = csr[EI];                                                          \
    float sc_ = als2[s_] + aldd;                                                     \
    sc_ = fmaxf(sc_, 0.2f * sc_);                                                    \
    const float w_ = exp2f(sc_);                                                     \
    wsum += w_;                                                                      \
    const uint2 hv_ = *reinterpret_cast<const uint2*>(h2 + (size_t)s_ * HID + 4 * sub); \
    a0 += w_ * __uint_as_float(hv_.x << 16);                                         \
    a1 += w_ * __uint_as_float(hv_.x & 0xffff0000u);                                 \
    a2 += w_ * __uint_as_float(hv_.y << 16);                                         \
    a3 += w_ * __uint_as_float(hv_.y & 0xffff0000u);                                 \
  }

  int e = r0;
  for (; e + 4 <= r1; e += 4) { M2_EDGE(e) M2_EDGE(e + 1) M2_EDGE(e + 2) M2_EDGE(e + 3) }
  for (; e < r1; ++e) { M2_EDGE(e) }

  const float inv = 1.f / (wsum + 1e-16f);
  const float4 bb = *reinterpret_cast<const float4*>(b2 + 4 * sub);
  float4 o;
  o.x = a0 * inv + bb.x;
  o.y = a1 * inv + bb.y;
  o.z = a2 * inv + bb.z;
  o.w = a3 * inv + bb.w;
  *reinterpret_cast<float4*>(out + (size_t)d * HID + 4 * sub) = o;
}

// ---------------- fused pool + classifier (4 waves/graph, unrolled MLP) ----------------

__device__ inline int lbound(const int* __restrict__ a, int n, int v) {
  int lo = 0, hi = n;
  while (lo < hi) { int m = (lo + hi) >> 1; if (a[m] < v) lo = m + 1; else hi = m; }
  return lo;
}

__global__ __launch_bounds__(256) void pool_cls_kernel(
    const float* __restrict__ out2, const int* __restrict__ batch,
    const float* __restrict__ Wc, const float* __restrict__ bc,
    float* __restrict__ out, int Nn, int C) {
  __shared__ float part[4][HID];
  __shared__ float es[HID];
  const int g = blockIdx.x;
  const int w = threadIdx.x >> 6;      // wave id: node-range slice
  const int t = threadIdx.x & 63;      // feature
  const int lo = lbound(batch, Nn, g);
  const int hi = lbound(batch, Nn, g + 1);
  float acc0 = 0.f, acc1 = 0.f, acc2 = 0.f, acc3 = 0.f;
  int n = lo + w;
  for (; n + 12 < hi; n += 16) {
    acc0 += out2[(size_t)(n) * HID + t];
    acc1 += out2[(size_t)(n + 4) * HID + t];
    acc2 += out2[(size_t)(n + 8) * HID + t];
    acc3 += out2[(size_t)(n + 12) * HID + t];
  }
  for (; n < hi; n += 4) acc0 += out2[(size_t)n * HID + t];
  part[w][t] = (acc0 + acc1) + (acc2 + acc3);
  __syncthreads();
  if (w == 0) {
    const int cnt = hi - lo;
    const float cf = (float)(cnt > 1 ? cnt : 1);
    es[t] = (part[0][t] + part[1][t] + part[2][t] + part[3][t]) / cf;
  }
  __syncthreads();
  for (int c = threadIdx.x; c < C; c += 256) {
    float a = bc[c];
#pragma unroll
    for (int d = 0; d < HID; ++d) a += es[d] * Wc[d * C + c];
    out[g * C + c] = a;
  }
}

extern "C" void kernel_launch(void* const* d_in, const int* in_sizes, int n_in,
                              void* d_out, int out_size, void* d_ws, size_t ws_size,
                              hipStream_t stream) {
  const float* x      = (const float*)d_in[0];
  const float* W1     = (const float*)d_in[1];
  const float* a_src1 = (const float*)d_in[2];
  const float* a_dst1 = (const float*)d_in[3];
  const float* b1     = (const float*)d_in[4];
  const float* W2     = (const float*)d_in[5];
  const float* a_src2 = (const float*)d_in[6];
  const float* a_dst2 = (const float*)d_in[7];
  const float* b2     = (const float*)d_in[8];
  const float* Wc     = (const float*)d_in[9];
  const float* bc     = (const float*)d_in[10];
  const int*   ei     = (const int*)d_in[11];
  const int*   batch  = (const int*)d_in[12];

  const int N = in_sizes[0] / HID;   // 50000
  const int E = in_sizes[11] / 2;    // 800000
  const int C = in_sizes[10];        // 120
  const int Etot = E + N;
  const int nbuck = (N + 255) >> 8;  // 196

  // workspace layout (all regions 16B-aligned)
  bf16_t* AGG = (bf16_t*)d_ws;                          // N*256 bf16; OUT2 f32 overlay later
  bf16_t* XBF = AGG + (size_t)N * C1;                   // N*64 bf16 -> h2 overlay
  float4* ALS1 = (float4*)(XBF + (size_t)N * HID);      // N float4 (scaled)
  float4* ALD1 = ALS1 + N;                              // N float4
  float* ALS2 = (float*)(ALD1 + N);                     // N f32 (scaled)
  float* ALD2 = ALS2 + N;                               // N f32
  int* ROWP   = (int*)(ALD2 + N);                       // N+4 (padded)
  int* BCNT   = ROWP + (N + 4);                         // 256
  int* CSR    = BCNT + 256;                             // Etot
  unsigned* EBUF = (unsigned*)(CSR + Etot);             // 256*BCAP
  float* VA   = (float*)(EBUF + 256 * BCAP);            // 512
  bf16_t* W1T = (bf16_t*)(VA + 512);                    // 16384 bf16
  bf16_t* W2T = W1T + 16384;                            // 16384 bf16

  bf16_t* H2B = XBF;                     // overlay (x_bf dead after msg1_agg)
  float* OUT2 = (float*)AGG;             // overlay (agg dead after gemm12_mfma)

  // ---- constants + BCNT zero (replaces memset dispatch) ----
  const_prep<<<64, 256, 0, stream>>>(W1, a_src1, a_dst1, W2, VA, W1T, W2T, BCNT);

  // ---- CSR build (bucket counting sort, all scatter in LDS) ----
  bin_kernel<<<(Etot + BIN_CHUNK - 1) / BIN_CHUNK, 256, 0, stream>>>(ei, BCNT, EBUF, E, N, nbuck);
  csr_kernel<<<nbuck, 256, 0, stream>>>(BCNT, EBUF, CSR, ROWP, N, nbuck);

  // ---- layer 1 ----
  prep_kernel<<<(N + 15) / 16, 256, 0, stream>>>(x, VA, XBF, ALS1, ALD1, N);
  msg1_agg<<<(N + 15) / 16, 256, 0, stream>>>(ROWP, CSR, ALS1, ALD1, XBF, AGG, N);

  // ---- fused dense chain on MFMA: agg -> x2 (LDS) -> h2, score scalars ----
  gemm12_mfma<<<(N + 15) / 16, 256, 0, stream>>>(AGG, W1T, b1, W2T, a_src2, a_dst2,
                                                 H2B, ALS2, ALD2, N);

  // ---- layer 2 aggregation ----
  msg2_fused<<<(N + 15) / 16, 256, 0, stream>>>(ROWP, CSR, ALS2, ALD2, H2B, b2, OUT2, N);

  // ---- pool + classifier ----
  pool_cls_kernel<<<NGRAPH, 256, 0, stream>>>(OUT2, batch, Wc, bc, (float*)d_out, N, C);
}

// Round 19
// 135.661 us; speedup vs baseline: 1.0546x; 1.0075x over previous
//
#include <hip/hip_runtime.h>
#include <cstdint>

#define HID 64
#define HEADS 4
#define C1 256   // HEADS*HID
#define NGRAPH 512
#define BCAP 5120       // per-bucket capacity (mean 4352, 12 sigma headroom)
#define BIN_CHUNK 4096  // edges per bin block
#define LOG2E 1.44269504f

typedef unsigned short bf16_t;
typedef __attribute__((ext_vector_type(8))) short short8v;   // 8 bf16 (4 VGPRs)
typedef __attribute__((ext_vector_type(4))) float f32x4;     // MFMA accumulator

__device__ inline bf16_t f2bf(float f) {  // round-to-nearest-even
  unsigned b = __float_as_uint(f);
  b += 0x7fffu + ((b >> 16) & 1u);
  return (bf16_t)(b >> 16);
}

// ---------------- merged constants prep: W transposes + va tables + BCNT zero ----------------

__global__ __launch_bounds__(256) void const_prep(
    const float* __restrict__ W1, const float* __restrict__ a_src,
    const float* __restrict__ a_dst, const float* __restrict__ W2,
    float* __restrict__ va, bf16_t* __restrict__ W1T, bf16_t* __restrict__ W2T,
    int* __restrict__ bcnt) {
  const int idx = blockIdx.x * 256 + threadIdx.x;  // 0..16383
  {
    const int c = idx >> 6, k = idx & 63;
    W1T[idx] = f2bf(W1[k * C1 + c]);
  }
  {
    const int c = idx >> 8, k = idx & 255;
    W2T[idx] = f2bf(W2[k * HID + c]);
  }
  if (blockIdx.x == 1) bcnt[threadIdx.x] = 0;   // replaces hipMemsetAsync dispatch
  if (blockIdx.x == 0) {
    const int t = threadIdx.x;       // t = h*64 + k
    const int h = t >> 6, k = t & 63;
    float s = 0.f, d = 0.f;
    for (int c = 0; c < 64; ++c) {
      const float w = W1[k * C1 + h * 64 + c];
      s += w * a_src[h * 64 + c];
      d += w * a_dst[h * 64 + c];
    }
    va[t] = s * LOG2E;         // pre-scaled for exp2
    va[256 + t] = d * LOG2E;
  }
}

// ---------------- prep: x -> x_bf (bf16) + scaled score tables (float4/node) ----------------

__global__ __launch_bounds__(256) void prep_kernel(
    const float* __restrict__ x, const float* __restrict__ va,
    bf16_t* __restrict__ xbf, float4* __restrict__ als, float4* __restrict__ ald,
    int Nn) {
  const int lane = threadIdx.x & 63;
  const int g = lane >> 4, sub = lane & 15;
  const int n = (blockIdx.x * 4 + (threadIdx.x >> 6)) * 4 + g;
  if (n >= Nn) return;
  const float4 xv = *reinterpret_cast<const float4*>(x + (size_t)n * HID + 4 * sub);
  ushort4 xb;
  xb.x = f2bf(xv.x); xb.y = f2bf(xv.y); xb.z = f2bf(xv.z); xb.w = f2bf(xv.w);
  *reinterpret_cast<ushort4*>(xbf + (size_t)n * HID + 4 * sub) = xb;
  float ps[HEADS], pd[HEADS];
#pragma unroll
  for (int h = 0; h < HEADS; ++h) {
    const float4 vs = *reinterpret_cast<const float4*>(va + h * 64 + 4 * sub);
    const float4 vd = *reinterpret_cast<const float4*>(va + 256 + h * 64 + 4 * sub);
    ps[h] = xv.x * vs.x + xv.y * vs.y + xv.z * vs.z + xv.w * vs.w;
    pd[h] = xv.x * vd.x + xv.y * vd.y + xv.z * vd.z + xv.w * vd.w;
  }
#pragma unroll
  for (int off = 1; off < 16; off <<= 1) {
#pragma unroll
    for (int h = 0; h < HEADS; ++h) {
      ps[h] += __shfl_xor(ps[h], off, 16);
      pd[h] += __shfl_xor(pd[h], off, 16);
    }
  }
  if (sub == 0) {
    als[n] = make_float4(ps[0], ps[1], ps[2], ps[3]);
    ald[n] = make_float4(pd[0], pd[1], pd[2], pd[3]);
  }
}

// ---------------- CSR build via LDS counting sort ----------------

__global__ __launch_bounds__(256) void bin_kernel(
    const int* __restrict__ ei, int* __restrict__ bcnt,
    unsigned* __restrict__ ebuf, int E, int Nn, int nbuck) {
  __shared__ unsigned ehold[BIN_CHUNK];
  __shared__ unsigned sorted[BIN_CHUNK];
  __shared__ unsigned char bkt[BIN_CHUNK];
  __shared__ unsigned char sbkt[BIN_CHUNK];
  __shared__ int hist[256], scanbuf[256], pref[256], ofs[256], gbase[256];
  const int t = threadIdx.x;
  const int base = blockIdx.x * BIN_CHUNK;
  const int total = E + Nn;
  const int m = min(BIN_CHUNK, total - base);
  if (m <= 0) return;

  hist[t] = 0;
  __syncthreads();
  for (int j = t; j < m; j += 256) {
    const int i = base + j;
    int s, d;
    if (i < E) { s = ei[i]; d = ei[E + i]; } else { s = d = i - E; }
    const int b = d >> 8;
    ehold[j] = ((unsigned)(d & 255) << 16) | (unsigned)s;
    bkt[j] = (unsigned char)b;
    atomicAdd(&hist[b], 1);
  }
  __syncthreads();
  const int v = hist[t];
  scanbuf[t] = v;
  __syncthreads();
  for (int off = 1; off < 256; off <<= 1) {
    const int p = (t >= off) ? scanbuf[t - off] : 0;
    __syncthreads();
    scanbuf[t] += p;
    __syncthreads();
  }
  pref[t] = scanbuf[t] - v;
  ofs[t] = 0;
  gbase[t] = (t < nbuck && v > 0) ? atomicAdd(&bcnt[t], v) : 0;
  __syncthreads();
  for (int j = t; j < m; j += 256) {
    const int b = bkt[j];
    const int r = atomicAdd(&ofs[b], 1);
    const int p = pref[b] + r;
    sorted[p] = ehold[j];
    sbkt[p] = (unsigned char)b;
  }
  __syncthreads();
  for (int j = t; j < m; j += 256) {
    const int b = sbkt[j];
    const int p = gbase[b] + (j - pref[b]);
    if (p < BCAP) ebuf[(size_t)b * BCAP + p] = sorted[j];
  }
}

__global__ __launch_bounds__(256) void csr_kernel(
    const int* __restrict__ bcnt, const unsigned* __restrict__ ebuf,
    int* __restrict__ csr, int* __restrict__ rowptr, int Nn, int nbuck) {
  __shared__ unsigned ent[BCAP];
  __shared__ unsigned short srt[BCAP];
  __shared__ int hist[256], scanbuf[256], pref[256], ofs[256];
  const int b = blockIdx.x, t = threadIdx.x;

  // parallel prefix over bucket counts
  const int bv = (t < nbuck) ? min(bcnt[t], BCAP) : 0;
  scanbuf[t] = bv;
  __syncthreads();
  for (int off = 1; off < 256; off <<= 1) {
    const int p = (t >= off) ? scanbuf[t - off] : 0;
    __syncthreads();
    scanbuf[t] += p;
    __syncthreads();
  }
  const int basev = (b > 0) ? scanbuf[b - 1] : 0;
  const int totalv = scanbuf[255];
  __syncthreads();  // scanbuf reused below

  const int m = min(bcnt[b], BCAP);
  hist[t] = 0;
  for (int j = t; j < m; j += 256) ent[j] = ebuf[(size_t)b * BCAP + j];
  __syncthreads();
  for (int j = t; j < m; j += 256) atomicAdd(&hist[ent[j] >> 16], 1);
  __syncthreads();
  const int v = hist[t];
  scanbuf[t] = v;
  __syncthreads();
  for (int off = 1; off < 256; off <<= 1) {
    const int p = (t >= off) ? scanbuf[t - off] : 0;
    __syncthreads();
    scanbuf[t] += p;
    __syncthreads();
  }
  pref[t] = scanbuf[t] - v;
  ofs[t] = 0;
  __syncthreads();
  const int d0 = b << 8;
  const int ndst = min(256, Nn - d0);
  if (t < ndst) rowptr[d0 + t] = basev + pref[t];
  if (b == 0 && t == 0) rowptr[Nn] = totalv;
  for (int j = t; j < m; j += 256) {
    const unsigned e = ent[j];
    const int dl = (int)(e >> 16);
    const int r = atomicAdd(&ofs[dl], 1);
    srt[pref[dl] + r] = (unsigned short)(e & 0xffffu);
  }
  __syncthreads();
  for (int j = t; j < m; j += 256) csr[basev + j] = (int)srt[j];
}

// ---------------- layer-1 aggregation v9: group-per-node, 16B gathers, reg weights ----------------

__global__ __launch_bounds__(256) void msg1_agg(
    const int* __restrict__ rowptr, const int* __restrict__ csr,
    const float4* __restrict__ als4, const float4* __restrict__ ald4,
    const bf16_t* __restrict__ xbf, bf16_t* __restrict__ agg, int Nn) {
  const int wid = threadIdx.x >> 6;
  const int lane = threadIdx.x & 63;
  const int l16 = lane & 15;
  const int epar = l16 >> 3;       // 0/1: which edge of the pair
  const int sub8 = l16 & 7;        // feature octet: feats 8*sub8..+7
  int d = (blockIdx.x * 4 + wid) * 4 + (lane >> 4);
  const bool dvalid = d < Nn;
  if (!dvalid) d = Nn - 1;
  const int r0 = rowptr[d], r1 = rowptr[d + 1];
  const float4 aldv = ald4[d];

  float acc[4][8];
#pragma unroll
  for (int h = 0; h < 4; ++h)
#pragma unroll
    for (int f = 0; f < 8; ++f) acc[h][f] = 0.f;
  float ws0 = 0.f, ws1 = 0.f, ws2 = 0.f, ws3 = 0.f;

  const int base = (lane & 48) + epar;   // group base for shfl index
  int cb = r0;
  int maxrem = r1 - cb;
  maxrem = max(maxrem, __shfl_xor(maxrem, 16, 64));
  maxrem = max(maxrem, __shfl_xor(maxrem, 32, 64));
  while (maxrem > 0) {
    const int eown = cb + l16;
    const int s_ = csr[min(eown, r1 - 1)];
    const float4 sv = als4[s_];
    float t0 = sv.x + aldv.x; t0 = fmaxf(t0, 0.2f * t0);
    float t1 = sv.y + aldv.y; t1 = fmaxf(t1, 0.2f * t1);
    float t2 = sv.z + aldv.z; t2 = fmaxf(t2, 0.2f * t2);
    float t3 = sv.w + aldv.w; t3 = fmaxf(t3, 0.2f * t3);
    float w0 = exp2f(t0), w1 = exp2f(t1), w2 = exp2f(t2), w3 = exp2f(t3);
    if (eown >= r1) { w0 = 0.f; w1 = 0.f; w2 = 0.f; w3 = 0.f; }
    ws0 += w0; ws1 += w1; ws2 += w2; ws3 += w3;
    const int nstep = (min(16, maxrem) + 1) >> 1;
    for (int t = 0; t < nstep; ++t) {
      const int idx = base + 2 * t;
      const float wj0 = __shfl(w0, idx, 64);
      const float wj1 = __shfl(w1, idx, 64);
      const float wj2 = __shfl(w2, idx, 64);
      const float wj3 = __shfl(w3, idx, 64);
      const int sj = __shfl(s_, idx, 64);
      const uint4 hv = *reinterpret_cast<const uint4*>(xbf + (size_t)sj * HID + 8 * sub8);
      float xv[8];
      xv[0] = __uint_as_float(hv.x << 16);
      xv[1] = __uint_as_float(hv.x & 0xffff0000u);
      xv[2] = __uint_as_float(hv.y << 16);
      xv[3] = __uint_as_float(hv.y & 0xffff0000u);
      xv[4] = __uint_as_float(hv.z << 16);
      xv[5] = __uint_as_float(hv.z & 0xffff0000u);
      xv[6] = __uint_as_float(hv.w << 16);
      xv[7] = __uint_as_float(hv.w & 0xffff0000u);
#pragma unroll
      for (int f = 0; f < 8; ++f) {
        acc[0][f] += wj0 * xv[f];
        acc[1][f] += wj1 * xv[f];
        acc[2][f] += wj2 * xv[f];
        acc[3][f] += wj3 * xv[f];
      }
    }
    cb += 16;
    maxrem = r1 - cb;
    maxrem = max(maxrem, __shfl_xor(maxrem, 16, 64));
    maxrem = max(maxrem, __shfl_xor(maxrem, 32, 64));
  }

#pragma unroll
  for (int off = 1; off < 16; off <<= 1) {
    ws0 += __shfl_xor(ws0, off, 64);
    ws1 += __shfl_xor(ws1, off, 64);
    ws2 += __shfl_xor(ws2, off, 64);
    ws3 += __shfl_xor(ws3, off, 64);
  }
#pragma unroll
  for (int h = 0; h < 4; ++h)
#pragma unroll
    for (int f = 0; f < 8; ++f) acc[h][f] += __shfl_xor(acc[h][f], 8, 64);

  if (dvalid) {
    const float i0 = 1.f / (ws0 + 1e-16f);
    const float i1 = 1.f / (ws1 + 1e-16f);
    const float i2 = 1.f / (ws2 + 1e-16f);
    const float i3 = 1.f / (ws3 + 1e-16f);
    float o0[8], o1[8];
#pragma unroll
    for (int f = 0; f < 8; ++f) {
      o0[f] = epar ? acc[2][f] : acc[0][f];
      o1[f] = epar ? acc[3][f] : acc[1][f];
    }
    const float iv0 = epar ? i2 : i0;
    const float iv1 = epar ? i3 : i1;
    const int h0 = epar * 2;
    uint4 p0, p1;
    p0.x = (unsigned)f2bf(o0[0] * iv0) | ((unsigned)f2bf(o0[1] * iv0) << 16);
    p0.y = (unsigned)f2bf(o0[2] * iv0) | ((unsigned)f2bf(o0[3] * iv0) << 16);
    p0.z = (unsigned)f2bf(o0[4] * iv0) | ((unsigned)f2bf(o0[5] * iv0) << 16);
    p0.w = (unsigned)f2bf(o0[6] * iv0) | ((unsigned)f2bf(o0[7] * iv0) << 16);
    p1.x = (unsigned)f2bf(o1[0] * iv1) | ((unsigned)f2bf(o1[1] * iv1) << 16);
    p1.y = (unsigned)f2bf(o1[2] * iv1) | ((unsigned)f2bf(o1[3] * iv1) << 16);
    p1.z = (unsigned)f2bf(o1[4] * iv1) | ((unsigned)f2bf(o1[5] * iv1) << 16);
    p1.w = (unsigned)f2bf(o1[6] * iv1) | ((unsigned)f2bf(o1[7] * iv1) << 16);
    *reinterpret_cast<uint4*>(agg + ((size_t)d * HEADS + h0) * HID + 8 * sub8) = p0;
    *reinterpret_cast<uint4*>(agg + ((size_t)d * HEADS + h0 + 1) * HID + 8 * sub8) = p1;
  }
}

// ---------------- fused dense chain on MFMA: 16 nodes/block, 4 waves ----------------

__global__ __launch_bounds__(256) void gemm12_mfma(
    const bf16_t* __restrict__ agg, const bf16_t* __restrict__ W1T,
    const float* __restrict__ b1, const bf16_t* __restrict__ W2T,
    const float* __restrict__ a2s, const float* __restrict__ a2d,
    bf16_t* __restrict__ h2, float* __restrict__ als2, float* __restrict__ ald2,
    int Nn) {
  __shared__ bf16_t x2s[16][264];     // x2 tile [node][col], 528B row stride
  __shared__ float pbuf_s[4][16], pbuf_d[4][16];
  const int w = threadIdx.x >> 6;     // wave id = head (ph1) / col quartile (ph2)
  const int l = threadIdx.x & 63;
  const int n0 = blockIdx.x * 16;
  if (n0 >= Nn) return;
  const int r16 = l & 15, g = l >> 4;

  const f32x4 zz = {0.f, 0.f, 0.f, 0.f};
  f32x4 acc1[4];
#pragma unroll
  for (int ct = 0; ct < 4; ++ct) acc1[ct] = zz;

  // ---- phase 1: head w, K=64 (2 MFMA K-steps x 4 col tiles) ----
  const bf16_t* arow = agg + (size_t)(n0 + r16) * C1 + w * 64;
#pragma unroll
  for (int ks = 0; ks < 2; ++ks) {
    const short8v bfrag = *reinterpret_cast<const short8v*>(arow + ks * 32 + g * 8);
#pragma unroll
    for (int ct = 0; ct < 4; ++ct) {
      const short8v afrag = *reinterpret_cast<const short8v*>(
          W1T + (size_t)(w * 64 + ct * 16 + r16) * 64 + ks * 32 + g * 8);
      acc1[ct] = __builtin_amdgcn_mfma_f32_16x16x32_bf16(afrag, bfrag, acc1[ct], 0, 0, 0);
    }
  }

  // bias + ELU (cheap exp-1) + bf16 pack -> LDS
#pragma unroll
  for (int ct = 0; ct < 4; ++ct) {
    const float4 bv = *reinterpret_cast<const float4*>(b1 + w * 64 + ct * 16 + g * 4);
    float v0 = acc1[ct][0] + bv.x;
    float v1 = acc1[ct][1] + bv.y;
    float v2 = acc1[ct][2] + bv.z;
    float v3 = acc1[ct][3] + bv.w;
    v0 = v0 > 0.f ? v0 : __expf(v0) - 1.f;
    v1 = v1 > 0.f ? v1 : __expf(v1) - 1.f;
    v2 = v2 > 0.f ? v2 : __expf(v2) - 1.f;
    v3 = v3 > 0.f ? v3 : __expf(v3) - 1.f;
    uint2 pk;
    pk.x = (unsigned)f2bf(v0) | ((unsigned)f2bf(v1) << 16);
    pk.y = (unsigned)f2bf(v2) | ((unsigned)f2bf(v3) << 16);
    *reinterpret_cast<uint2*>(&x2s[r16][w * 64 + ct * 16 + g * 4]) = pk;
  }
  __syncthreads();

  // ---- phase 2: h2 col block w*16..w*16+15, K=256 (8 MFMA K-steps) ----
  f32x4 acc2 = zz;
#pragma unroll
  for (int s2 = 0; s2 < 8; ++s2) {
    const short8v bfrag = *reinterpret_cast<const short8v*>(&x2s[r16][s2 * 32 + g * 8]);
    const short8v afrag = *reinterpret_cast<const short8v*>(
        W2T + (size_t)(w * 16 + r16) * 256 + s2 * 32 + g * 8);
    acc2 = __builtin_amdgcn_mfma_f32_16x16x32_bf16(afrag, bfrag, acc2, 0, 0, 0);
  }

  // epilogue: h2 bf16 write + score partials
  const float4 avs = *reinterpret_cast<const float4*>(a2s + w * 16 + g * 4);
  const float4 avd = *reinterpret_cast<const float4*>(a2d + w * 16 + g * 4);
  float ps = acc2[0] * avs.x + acc2[1] * avs.y + acc2[2] * avs.z + acc2[3] * avs.w;
  float pd = acc2[0] * avd.x + acc2[1] * avd.y + acc2[2] * avd.z + acc2[3] * avd.w;
  ushort4 hb;
  hb.x = f2bf(acc2[0]); hb.y = f2bf(acc2[1]);
  hb.z = f2bf(acc2[2]); hb.w = f2bf(acc2[3]);
  *reinterpret_cast<ushort4*>(h2 + (size_t)(n0 + r16) * HID + w * 16 + g * 4) = hb;
  ps += __shfl_xor(ps, 16, 64);
  ps += __shfl_xor(ps, 32, 64);
  pd += __shfl_xor(pd, 16, 64);
  pd += __shfl_xor(pd, 32, 64);
  if (g == 0) { pbuf_s[w][r16] = ps; pbuf_d[w][r16] = pd; }
  __syncthreads();
  if (w == 0 && g == 0) {
    const float pst = pbuf_s[0][r16] + pbuf_s[1][r16] + pbuf_s[2][r16] + pbuf_s[3][r16];
    const float pdt = pbuf_d[0][r16] + pbuf_d[1][r16] + pbuf_d[2][r16] + pbuf_d[3][r16];
    als2[n0 + r16] = pst * LOG2E;
    ald2[n0 + r16] = pdt * LOG2E;
  }
}

// ---------------- layer-2 aggregation v2: group-per-node, weights once, 16B gathers ----------------
// 4 nodes/wave; 16 lanes/node: epar = edge parity, sub8 = feature octet (8 feats).
// Weight phase: lane l16 owns edge cb+l16 -> ONE exp2 per edge (was 16x redundant).

__global__ __launch_bounds__(256) void msg2_fused(
    const int* __restrict__ rowptr, const int* __restrict__ csr,
    const float* __restrict__ als2, const float* __restrict__ ald2,
    const bf16_t* __restrict__ h2, const float* __restrict__ b2,
    float* __restrict__ out, int Nn) {
  const int wid = threadIdx.x >> 6;
  const int lane = threadIdx.x & 63;
  const int l16 = lane & 15;
  const int epar = l16 >> 3;
  const int sub8 = l16 & 7;
  int d = (blockIdx.x * 4 + wid) * 4 + (lane >> 4);
  const bool dvalid = d < Nn;
  if (!dvalid) d = Nn - 1;
  const int r0 = rowptr[d], r1 = rowptr[d + 1];
  const float aldd = ald2[d];

  float acc[8];
#pragma unroll
  for (int f = 0; f < 8; ++f) acc[f] = 0.f;
  float ws = 0.f;

  const int base = (lane & 48) + epar;
  int cb = r0;
  int maxrem = r1 - cb;
  maxrem = max(maxrem, __shfl_xor(maxrem, 16, 64));
  maxrem = max(maxrem, __shfl_xor(maxrem, 32, 64));
  while (maxrem > 0) {
    // weight phase: lane l16 owns edge cb+l16, ONE exp2
    const int eown = cb + l16;
    const int s_ = csr[min(eown, r1 - 1)];
    float sc = als2[s_] + aldd;
    sc = fmaxf(sc, 0.2f * sc);
    float w = exp2f(sc);
    if (eown >= r1) w = 0.f;
    ws += w;
    // gather: 2 edges/step via epar halves, mask-free (zero weights)
    const int nstep = (min(16, maxrem) + 1) >> 1;
    for (int t = 0; t < nstep; ++t) {
      const int idx = base + 2 * t;
      const float wj = __shfl(w, idx, 64);
      const int sj = __shfl(s_, idx, 64);
      const uint4 hv = *reinterpret_cast<const uint4*>(h2 + (size_t)sj * HID + 8 * sub8);
      acc[0] += wj * __uint_as_float(hv.x << 16);
      acc[1] += wj * __uint_as_float(hv.x & 0xffff0000u);
      acc[2] += wj * __uint_as_float(hv.y << 16);
      acc[3] += wj * __uint_as_float(hv.y & 0xffff0000u);
      acc[4] += wj * __uint_as_float(hv.z << 16);
      acc[5] += wj * __uint_as_float(hv.z & 0xffff0000u);
      acc[6] += wj * __uint_as_float(hv.w << 16);
      acc[7] += wj * __uint_as_float(hv.w & 0xffff0000u);
    }
    cb += 16;
    maxrem = r1 - cb;
    maxrem = max(maxrem, __shfl_xor(maxrem, 16, 64));
    maxrem = max(maxrem, __shfl_xor(maxrem, 32, 64));
  }

  // ws: reduce over the 16 lanes of the group
#pragma unroll
  for (int off = 1; off < 16; off <<= 1) ws += __shfl_xor(ws, off, 64);
  // acc: merge the two epar halves
#pragma unroll
  for (int f = 0; f < 8; ++f) acc[f] += __shfl_xor(acc[f], 8, 64);

  if (dvalid) {
    const float inv = 1.f / (ws + 1e-16f);
    // epar 0 writes feats 8*sub8..+3, epar 1 writes 8*sub8+4..+7
    const int fo = 8 * sub8 + 4 * epar;
    const float4 bb = *reinterpret_cast<const float4*>(b2 + fo);
    float4 o;
    o.x = (epar ? acc[4] : acc[0]) * inv + bb.x;
    o.y = (epar ? acc[5] : acc[1]) * inv + bb.y;
    o.z = (epar ? acc[6] : acc[2]) * inv + bb.z;
    o.w = (epar ? acc[7] : acc[3]) * inv + bb.w;
    *reinterpret_cast<float4*>(out + (size_t)d * HID + fo) = o;
  }
}

// ---------------- fused pool + classifier (4 waves/graph, unrolled MLP) ----------------

__device__ inline int lbound(const int* __restrict__ a, int n, int v) {
  int lo = 0, hi = n;
  while (lo < hi) { int m = (lo + hi) >> 1; if (a[m] < v) lo = m + 1; else hi = m; }
  return lo;
}

__global__ __launch_bounds__(256) void pool_cls_kernel(
    const float* __restrict__ out2, const int* __restrict__ batch,
    const float* __restrict__ Wc, const float* __restrict__ bc,
    float* __restrict__ out, int Nn, int C) {
  __shared__ float part[4][HID];
  __shared__ float es[HID];
  const int g = blockIdx.x;
  const int w = threadIdx.x >> 6;      // wave id: node-range slice
  const int t = threadIdx.x & 63;      // feature
  const int lo = lbound(batch, Nn, g);
  const int hi = lbound(batch, Nn, g + 1);
  float acc0 = 0.f, acc1 = 0.f, acc2 = 0.f, acc3 = 0.f;
  int n = lo + w;
  for (; n + 12 < hi; n += 16) {
    acc0 += out2[(size_t)(n) * HID + t];
    acc1 += out2[(size_t)(n + 4) * HID + t];
    acc2 += out2[(size_t)(n + 8) * HID + t];
    acc3 += out2[(size_t)(n + 12) * HID + t];
  }
  for (; n < hi; n += 4) acc0 += out2[(size_t)n * HID + t];
  part[w][t] = (acc0 + acc1) + (acc2 + acc3);
  __syncthreads();
  if (w == 0) {
    const int cnt = hi - lo;
    const float cf = (float)(cnt > 1 ? cnt : 1);
    es[t] = (part[0][t] + part[1][t] + part[2][t] + part[3][t]) / cf;
  }
  __syncthreads();
  for (int c = threadIdx.x; c < C; c += 256) {
    float a = bc[c];
#pragma unroll
    for (int d = 0; d < HID; ++d) a += es[d] * Wc[d * C + c];
    out[g * C + c] = a;
  }
}

extern "C" void kernel_launch(void* const* d_in, const int* in_sizes, int n_in,
                              void* d_out, int out_size, void* d_ws, size_t ws_size,
                              hipStream_t stream) {
  const float* x      = (const float*)d_in[0];
  const float* W1     = (const float*)d_in[1];
  const float* a_src1 = (const float*)d_in[2];
  const float* a_dst1 = (const float*)d_in[3];
  const float* b1     = (const float*)d_in[4];
  const float* W2     = (const float*)d_in[5];
  const float* a_src2 = (const float*)d_in[6];
  const float* a_dst2 = (const float*)d_in[7];
  const float* b2     = (const float*)d_in[8];
  const float* Wc     = (const float*)d_in[9];
  const float* bc     = (const float*)d_in[10];
  const int*   ei     = (const int*)d_in[11];
  const int*   batch  = (const int*)d_in[12];

  const int N = in_sizes[0] / HID;   // 50000
  const int E = in_sizes[11] / 2;    // 800000
  const int C = in_sizes[10];        // 120
  const int Etot = E + N;
  const int nbuck = (N + 255) >> 8;  // 196

  // workspace layout (all regions 16B-aligned)
  bf16_t* AGG = (bf16_t*)d_ws;                          // N*256 bf16; OUT2 f32 overlay later
  bf16_t* XBF = AGG + (size_t)N * C1;                   // N*64 bf16 -> h2 overlay
  float4* ALS1 = (float4*)(XBF + (size_t)N * HID);      // N float4 (scaled)
  float4* ALD1 = ALS1 + N;                              // N float4
  float* ALS2 = (float*)(ALD1 + N);                     // N f32 (scaled)
  float* ALD2 = ALS2 + N;                               // N f32
  int* ROWP   = (int*)(ALD2 + N);                       // N+4 (padded)
  int* BCNT   = ROWP + (N + 4);                         // 256
  int* CSR    = BCNT + 256;                             // Etot
  unsigned* EBUF = (unsigned*)(CSR + Etot);             // 256*BCAP
  float* VA   = (float*)(EBUF + 256 * BCAP);            // 512
  bf16_t* W1T = (bf16_t*)(VA + 512);                    // 16384 bf16
  bf16_t* W2T = W1T + 16384;                            // 16384 bf16

  bf16_t* H2B = XBF;                     // overlay (x_bf dead after msg1_agg)
  float* OUT2 = (float*)AGG;             // overlay (agg dead after gemm12_mfma)

  // ---- constants + BCNT zero (replaces memset dispatch) ----
  const_prep<<<64, 256, 0, stream>>>(W1, a_src1, a_dst1, W2, VA, W1T, W2T, BCNT);

  // ---- CSR build (bucket counting sort, all scatter in LDS) ----
  bin_kernel<<<(Etot + BIN_CHUNK - 1) / BIN_CHUNK, 256, 0, stream>>>(ei, BCNT, EBUF, E, N, nbuck);
  csr_kernel<<<nbuck, 256, 0, stream>>>(BCNT, EBUF, CSR, ROWP, N, nbuck);

  // ---- layer 1 ----
  prep_kernel<<<(N + 15) / 16, 256, 0, stream>>>(x, VA, XBF, ALS1, ALD1, N);
  msg1_agg<<<(N + 15) / 16, 256, 0, stream>>>(ROWP, CSR, ALS1, ALD1, XBF, AGG, N);

  // ---- fused dense chain on MFMA: agg -> x2 (LDS) -> h2, score scalars ----
  gemm12_mfma<<<(N + 15) / 16, 256, 0, stream>>>(AGG, W1T, b1, W2T, a_src2, a_dst2,
                                                 H2B, ALS2, ALD2, N);

  // ---- layer 2 aggregation ----
  msg2_fused<<<(N + 15) / 16, 256, 0, stream>>>(ROWP, CSR, ALS2, ALD2, H2B, b2, OUT2, N);

  // ---- pool + classifier ----
  pool_cls_kernel<<<NGRAPH, 256, 0, stream>>>(OUT2, batch, Wc, bc, (float*)d_out, N, C);
}

// Round 20
// 133.609 us; speedup vs baseline: 1.0708x; 1.0154x over previous
//
#include <hip/hip_runtime.h>
#include <cstdint>

#define HID 64
#define HEADS 4
#define C1 256   // HEADS*HID
#define NGRAPH 512
#define BCAP 5120       // per-bucket capacity (mean 4352, 12 sigma headroom)
#define BIN_CHUNK 4096  // edges per bin block
#define LOG2E 1.44269504f

typedef unsigned short bf16_t;
typedef __attribute__((ext_vector_type(8))) short short8v;   // 8 bf16 (4 VGPRs)
typedef __attribute__((ext_vector_type(4))) float f32x4;     // MFMA accumulator

__device__ inline bf16_t f2bf(float f) {  // round-to-nearest-even
  unsigned b = __float_as_uint(f);
  b += 0x7fffu + ((b >> 16) & 1u);
  return (bf16_t)(b >> 16);
}

// ---------------- merged constants prep: W transposes + va tables + BCNT zero ----------------

__global__ __launch_bounds__(256) void const_prep(
    const float* __restrict__ W1, const float* __restrict__ a_src,
    const float* __restrict__ a_dst, const float* __restrict__ W2,
    float* __restrict__ va, bf16_t* __restrict__ W1T, bf16_t* __restrict__ W2T,
    int* __restrict__ bcnt) {
  const int idx = blockIdx.x * 256 + threadIdx.x;  // 0..16383
  {
    const int c = idx >> 6, k = idx & 63;
    W1T[idx] = f2bf(W1[k * C1 + c]);
  }
  {
    const int c = idx >> 8, k = idx & 255;
    W2T[idx] = f2bf(W2[k * HID + c]);
  }
  if (blockIdx.x == 1) bcnt[threadIdx.x] = 0;   // replaces hipMemsetAsync dispatch
  if (blockIdx.x == 0) {
    const int t = threadIdx.x;       // t = h*64 + k
    const int h = t >> 6, k = t & 63;
    float s = 0.f, d = 0.f;
    for (int c = 0; c < 64; ++c) {
      const float w = W1[k * C1 + h * 64 + c];
      s += w * a_src[h * 64 + c];
      d += w * a_dst[h * 64 + c];
    }
    va[t] = s * LOG2E;         // pre-scaled for exp2
    va[256 + t] = d * LOG2E;
  }
}

// ---------------- prep: x -> x_bf (bf16) + scaled score tables (float4/node) ----------------

__global__ __launch_bounds__(256) void prep_kernel(
    const float* __restrict__ x, const float* __restrict__ va,
    bf16_t* __restrict__ xbf, float4* __restrict__ als, float4* __restrict__ ald,
    int Nn) {
  const int lane = threadIdx.x & 63;
  const int g = lane >> 4, sub = lane & 15;
  const int n = (blockIdx.x * 4 + (threadIdx.x >> 6)) * 4 + g;
  if (n >= Nn) return;
  const float4 xv = *reinterpret_cast<const float4*>(x + (size_t)n * HID + 4 * sub);
  ushort4 xb;
  xb.x = f2bf(xv.x); xb.y = f2bf(xv.y); xb.z = f2bf(xv.z); xb.w = f2bf(xv.w);
  *reinterpret_cast<ushort4*>(xbf + (size_t)n * HID + 4 * sub) = xb;
  float ps[HEADS], pd[HEADS];
#pragma unroll
  for (int h = 0; h < HEADS; ++h) {
    const float4 vs = *reinterpret_cast<const float4*>(va + h * 64 + 4 * sub);
    const float4 vd = *reinterpret_cast<const float4*>(va + 256 + h * 64 + 4 * sub);
    ps[h] = xv.x * vs.x + xv.y * vs.y + xv.z * vs.z + xv.w * vs.w;
    pd[h] = xv.x * vd.x + xv.y * vd.y + xv.z * vd.z + xv.w * vd.w;
  }
#pragma unroll
  for (int off = 1; off < 16; off <<= 1) {
#pragma unroll
    for (int h = 0; h < HEADS; ++h) {
      ps[h] += __shfl_xor(ps[h], off, 16);
      pd[h] += __shfl_xor(pd[h], off, 16);
    }
  }
  if (sub == 0) {
    als[n] = make_float4(ps[0], ps[1], ps[2], ps[3]);
    ald[n] = make_float4(pd[0], pd[1], pd[2], pd[3]);
  }
}

// ---------------- CSR build via LDS counting sort ----------------

__global__ __launch_bounds__(256) void bin_kernel(
    const int* __restrict__ ei, int* __restrict__ bcnt,
    unsigned* __restrict__ ebuf, int E, int Nn, int nbuck) {
  __shared__ unsigned ehold[BIN_CHUNK];
  __shared__ unsigned sorted[BIN_CHUNK];
  __shared__ unsigned char bkt[BIN_CHUNK];
  __shared__ unsigned char sbkt[BIN_CHUNK];
  __shared__ int hist[256], scanbuf[256], pref[256], ofs[256], gbase[256];
  const int t = threadIdx.x;
  const int base = blockIdx.x * BIN_CHUNK;
  const int total = E + Nn;
  const int m = min(BIN_CHUNK, total - base);
  if (m <= 0) return;

  hist[t] = 0;
  __syncthreads();
  for (int j = t; j < m; j += 256) {
    const int i = base + j;
    int s, d;
    if (i < E) { s = ei[i]; d = ei[E + i]; } else { s = d = i - E; }
    const int b = d >> 8;
    ehold[j] = ((unsigned)(d & 255) << 16) | (unsigned)s;
    bkt[j] = (unsigned char)b;
    atomicAdd(&hist[b], 1);
  }
  __syncthreads();
  const int v = hist[t];
  scanbuf[t] = v;
  __syncthreads();
  for (int off = 1; off < 256; off <<= 1) {
    const int p = (t >= off) ? scanbuf[t - off] : 0;
    __syncthreads();
    scanbuf[t] += p;
    __syncthreads();
  }
  pref[t] = scanbuf[t] - v;
  ofs[t] = 0;
  gbase[t] = (t < nbuck && v > 0) ? atomicAdd(&bcnt[t], v) : 0;
  __syncthreads();
  for (int j = t; j < m; j += 256) {
    const int b = bkt[j];
    const int r = atomicAdd(&ofs[b], 1);
    const int p = pref[b] + r;
    sorted[p] = ehold[j];
    sbkt[p] = (unsigned char)b;
  }
  __syncthreads();
  for (int j = t; j < m; j += 256) {
    const int b = sbkt[j];
    const int p = gbase[b] + (j - pref[b]);
    if (p < BCAP) ebuf[(size_t)b * BCAP + p] = sorted[j];
  }
}

__global__ __launch_bounds__(256) void csr_kernel(
    const int* __restrict__ bcnt, const unsigned* __restrict__ ebuf,
    int* __restrict__ csr, int* __restrict__ rowptr, int Nn, int nbuck) {
  __shared__ unsigned ent[BCAP];
  __shared__ unsigned short srt[BCAP];
  __shared__ int hist[256], scanbuf[256], pref[256], ofs[256];
  const int b = blockIdx.x, t = threadIdx.x;

  // parallel prefix over bucket counts
  const int bv = (t < nbuck) ? min(bcnt[t], BCAP) : 0;
  scanbuf[t] = bv;
  __syncthreads();
  for (int off = 1; off < 256; off <<= 1) {
    const int p = (t >= off) ? scanbuf[t - off] : 0;
    __syncthreads();
    scanbuf[t] += p;
    __syncthreads();
  }
  const int basev = (b > 0) ? scanbuf[b - 1] : 0;
  const int totalv = scanbuf[255];
  __syncthreads();  // scanbuf reused below

  const int m = min(bcnt[b], BCAP);
  hist[t] = 0;
  for (int j = t; j < m; j += 256) ent[j] = ebuf[(size_t)b * BCAP + j];
  __syncthreads();
  for (int j = t; j < m; j += 256) atomicAdd(&hist[ent[j] >> 16], 1);
  __syncthreads();
  const int v = hist[t];
  scanbuf[t] = v;
  __syncthreads();
  for (int off = 1; off < 256; off <<= 1) {
    const int p = (t >= off) ? scanbuf[t - off] : 0;
    __syncthreads();
    scanbuf[t] += p;
    __syncthreads();
  }
  pref[t] = scanbuf[t] - v;
  ofs[t] = 0;
  __syncthreads();
  const int d0 = b << 8;
  const int ndst = min(256, Nn - d0);
  if (t < ndst) rowptr[d0 + t] = basev + pref[t];
  if (b == 0 && t == 0) rowptr[Nn] = totalv;
  for (int j = t; j < m; j += 256) {
    const unsigned e = ent[j];
    const int dl = (int)(e >> 16);
    const int r = atomicAdd(&ofs[dl], 1);
    srt[pref[dl] + r] = (unsigned short)(e & 0xffffu);
  }
  __syncthreads();
  for (int j = t; j < m; j += 256) csr[basev + j] = (int)srt[j];
}

// ---------------- layer-1 aggregation v10: v9 + 2-deep pipelined gather ----------------

__global__ __launch_bounds__(256) void msg1_agg(
    const int* __restrict__ rowptr, const int* __restrict__ csr,
    const float4* __restrict__ als4, const float4* __restrict__ ald4,
    const bf16_t* __restrict__ xbf, bf16_t* __restrict__ agg, int Nn) {
  const int wid = threadIdx.x >> 6;
  const int lane = threadIdx.x & 63;
  const int l16 = lane & 15;
  const int epar = l16 >> 3;       // 0/1: which edge of the pair
  const int sub8 = l16 & 7;        // feature octet: feats 8*sub8..+7
  int d = (blockIdx.x * 4 + wid) * 4 + (lane >> 4);
  const bool dvalid = d < Nn;
  if (!dvalid) d = Nn - 1;
  const int r0 = rowptr[d], r1 = rowptr[d + 1];
  const float4 aldv = ald4[d];

  float acc[4][8];
#pragma unroll
  for (int h = 0; h < 4; ++h)
#pragma unroll
    for (int f = 0; f < 8; ++f) acc[h][f] = 0.f;
  float ws0 = 0.f, ws1 = 0.f, ws2 = 0.f, ws3 = 0.f;

  const int base = (lane & 48) + epar;   // group base for shfl index
  int cb = r0;
  int maxrem = r1 - cb;
  maxrem = max(maxrem, __shfl_xor(maxrem, 16, 64));
  maxrem = max(maxrem, __shfl_xor(maxrem, 32, 64));

#define M1_STEP_FMA(HV, J0, J1, J2, J3) {                                           \
    float xv[8];                                                                    \
    xv[0] = __uint_as_float(HV.x << 16);                                            \
    xv[1] = __uint_as_float(HV.x & 0xffff0000u);                                    \
    xv[2] = __uint_as_float(HV.y << 16);                                            \
    xv[3] = __uint_as_float(HV.y & 0xffff0000u);                                    \
    xv[4] = __uint_as_float(HV.z << 16);                                            \
    xv[5] = __uint_as_float(HV.z & 0xffff0000u);                                    \
    xv[6] = __uint_as_float(HV.w << 16);                                            \
    xv[7] = __uint_as_float(HV.w & 0xffff0000u);                                    \
    _Pragma("unroll")                                                               \
    for (int f = 0; f < 8; ++f) {                                                   \
      acc[0][f] += J0 * xv[f];                                                      \
      acc[1][f] += J1 * xv[f];                                                      \
      acc[2][f] += J2 * xv[f];                                                      \
      acc[3][f] += J3 * xv[f];                                                      \
    }                                                                               \
  }

  while (maxrem > 0) {
    const int eown = cb + l16;
    const int s_ = csr[min(eown, r1 - 1)];
    const float4 sv = als4[s_];
    float t0 = sv.x + aldv.x; t0 = fmaxf(t0, 0.2f * t0);
    float t1 = sv.y + aldv.y; t1 = fmaxf(t1, 0.2f * t1);
    float t2 = sv.z + aldv.z; t2 = fmaxf(t2, 0.2f * t2);
    float t3 = sv.w + aldv.w; t3 = fmaxf(t3, 0.2f * t3);
    float w0 = exp2f(t0), w1 = exp2f(t1), w2 = exp2f(t2), w3 = exp2f(t3);
    if (eown >= r1) { w0 = 0.f; w1 = 0.f; w2 = 0.f; w3 = 0.f; }
    ws0 += w0; ws1 += w1; ws2 += w2; ws3 += w3;
    const int nstep = (min(16, maxrem) + 1) >> 1;
    int t = 0;
    // 2-deep pipelined: index shfls + both loads issued before the weight shfls/FMAs
    for (; t + 2 <= nstep; t += 2) {
      const int idxA = base + 2 * t;
      const int idxB = idxA + 2;
      const int sjA = __shfl(s_, idxA, 64);
      const int sjB = __shfl(s_, idxB, 64);
      const uint4 hvA = *reinterpret_cast<const uint4*>(xbf + (size_t)sjA * HID + 8 * sub8);
      const uint4 hvB = *reinterpret_cast<const uint4*>(xbf + (size_t)sjB * HID + 8 * sub8);
      const float a0 = __shfl(w0, idxA, 64), b0 = __shfl(w0, idxB, 64);
      const float a1 = __shfl(w1, idxA, 64), b1 = __shfl(w1, idxB, 64);
      const float a2 = __shfl(w2, idxA, 64), b2 = __shfl(w2, idxB, 64);
      const float a3 = __shfl(w3, idxA, 64), b3 = __shfl(w3, idxB, 64);
      M1_STEP_FMA(hvA, a0, a1, a2, a3)
      M1_STEP_FMA(hvB, b0, b1, b2, b3)
    }
    if (t < nstep) {
      const int idxA = base + 2 * t;
      const int sjA = __shfl(s_, idxA, 64);
      const uint4 hvA = *reinterpret_cast<const uint4*>(xbf + (size_t)sjA * HID + 8 * sub8);
      const float a0 = __shfl(w0, idxA, 64);
      const float a1 = __shfl(w1, idxA, 64);
      const float a2 = __shfl(w2, idxA, 64);
      const float a3 = __shfl(w3, idxA, 64);
      M1_STEP_FMA(hvA, a0, a1, a2, a3)
    }
    cb += 16;
    maxrem = r1 - cb;
    maxrem = max(maxrem, __shfl_xor(maxrem, 16, 64));
    maxrem = max(maxrem, __shfl_xor(maxrem, 32, 64));
  }

#pragma unroll
  for (int off = 1; off < 16; off <<= 1) {
    ws0 += __shfl_xor(ws0, off, 64);
    ws1 += __shfl_xor(ws1, off, 64);
    ws2 += __shfl_xor(ws2, off, 64);
    ws3 += __shfl_xor(ws3, off, 64);
  }
#pragma unroll
  for (int h = 0; h < 4; ++h)
#pragma unroll
    for (int f = 0; f < 8; ++f) acc[h][f] += __shfl_xor(acc[h][f], 8, 64);

  if (dvalid) {
    const float i0 = 1.f / (ws0 + 1e-16f);
    const float i1 = 1.f / (ws1 + 1e-16f);
    const float i2 = 1.f / (ws2 + 1e-16f);
    const float i3 = 1.f / (ws3 + 1e-16f);
    float o0[8], o1[8];
#pragma unroll
    for (int f = 0; f < 8; ++f) {
      o0[f] = epar ? acc[2][f] : acc[0][f];
      o1[f] = epar ? acc[3][f] : acc[1][f];
    }
    const float iv0 = epar ? i2 : i0;
    const float iv1 = epar ? i3 : i1;
    const int h0 = epar * 2;
    uint4 p0, p1;
    p0.x = (unsigned)f2bf(o0[0] * iv0) | ((unsigned)f2bf(o0[1] * iv0) << 16);
    p0.y = (unsigned)f2bf(o0[2] * iv0) | ((unsigned)f2bf(o0[3] * iv0) << 16);
    p0.z = (unsigned)f2bf(o0[4] * iv0) | ((unsigned)f2bf(o0[5] * iv0) << 16);
    p0.w = (unsigned)f2bf(o0[6] * iv0) | ((unsigned)f2bf(o0[7] * iv0) << 16);
    p1.x = (unsigned)f2bf(o1[0] * iv1) | ((unsigned)f2bf(o1[1] * iv1) << 16);
    p1.y = (unsigned)f2bf(o1[2] * iv1) | ((unsigned)f2bf(o1[3] * iv1) << 16);
    p1.z = (unsigned)f2bf(o1[4] * iv1) | ((unsigned)f2bf(o1[5] * iv1) << 16);
    p1.w = (unsigned)f2bf(o1[6] * iv1) | ((unsigned)f2bf(o1[7] * iv1) << 16);
    *reinterpret_cast<uint4*>(agg + ((size_t)d * HEADS + h0) * HID + 8 * sub8) = p0;
    *reinterpret_cast<uint4*>(agg + ((size_t)d * HEADS + h0 + 1) * HID + 8 * sub8) = p1;
  }
}

// ---------------- fused dense chain on MFMA: 16 nodes/block, 4 waves ----------------

__global__ __launch_bounds__(256) void gemm12_mfma(
    const bf16_t* __restrict__ agg, const bf16_t* __restrict__ W1T,
    const float* __restrict__ b1, const bf16_t* __restrict__ W2T,
    const float* __restrict__ a2s, const float* __restrict__ a2d,
    bf16_t* __restrict__ h2, float* __restrict__ als2, float* __restrict__ ald2,
    int Nn) {
  __shared__ bf16_t x2s[16][264];     // x2 tile [node][col], 528B row stride
  __shared__ float pbuf_s[4][16], pbuf_d[4][16];
  const int w = threadIdx.x >> 6;     // wave id = head (ph1) / col quartile (ph2)
  const int l = threadIdx.x & 63;
  const int n0 = blockIdx.x * 16;
  if (n0 >= Nn) return;
  const int r16 = l & 15, g = l >> 4;

  const f32x4 zz = {0.f, 0.f, 0.f, 0.f};
  f32x4 acc1[4];
#pragma unroll
  for (int ct = 0; ct < 4; ++ct) acc1[ct] = zz;

  // ---- phase 1: head w, K=64 (2 MFMA K-steps x 4 col tiles) ----
  const bf16_t* arow = agg + (size_t)(n0 + r16) * C1 + w * 64;
#pragma unroll
  for (int ks = 0; ks < 2; ++ks) {
    const short8v bfrag = *reinterpret_cast<const short8v*>(arow + ks * 32 + g * 8);
#pragma unroll
    for (int ct = 0; ct < 4; ++ct) {
      const short8v afrag = *reinterpret_cast<const short8v*>(
          W1T + (size_t)(w * 64 + ct * 16 + r16) * 64 + ks * 32 + g * 8);
      acc1[ct] = __builtin_amdgcn_mfma_f32_16x16x32_bf16(afrag, bfrag, acc1[ct], 0, 0, 0);
    }
  }

  // bias + ELU (cheap exp-1) + bf16 pack -> LDS
#pragma unroll
  for (int ct = 0; ct < 4; ++ct) {
    const float4 bv = *reinterpret_cast<const float4*>(b1 + w * 64 + ct * 16 + g * 4);
    float v0 = acc1[ct][0] + bv.x;
    float v1 = acc1[ct][1] + bv.y;
    float v2 = acc1[ct][2] + bv.z;
    float v3 = acc1[ct][3] + bv.w;
    v0 = v0 > 0.f ? v0 : __expf(v0) - 1.f;
    v1 = v1 > 0.f ? v1 : __expf(v1) - 1.f;
    v2 = v2 > 0.f ? v2 : __expf(v2) - 1.f;
    v3 = v3 > 0.f ? v3 : __expf(v3) - 1.f;
    uint2 pk;
    pk.x = (unsigned)f2bf(v0) | ((unsigned)f2bf(v1) << 16);
    pk.y = (unsigned)f2bf(v2) | ((unsigned)f2bf(v3) << 16);
    *reinterpret_cast<uint2*>(&x2s[r16][w * 64 + ct * 16 + g * 4]) = pk;
  }
  __syncthreads();

  // ---- phase 2: h2 col block w*16..w*16+15, K=256 (8 MFMA K-steps) ----
  f32x4 acc2 = zz;
#pragma unroll
  for (int s2 = 0; s2 < 8; ++s2) {
    const short8v bfrag = *reinterpret_cast<const short8v*>(&x2s[r16][s2 * 32 + g * 8]);
    const short8v afrag = *reinterpret_cast<const short8v*>(
        W2T + (size_t)(w * 16 + r16) * 256 + s2 * 32 + g * 8);
    acc2 = __builtin_amdgcn_mfma_f32_16x16x32_bf16(afrag, bfrag, acc2, 0, 0, 0);
  }

  // epilogue: h2 bf16 write + score partials
  const float4 avs = *reinterpret_cast<const float4*>(a2s + w * 16 + g * 4);
  const float4 avd = *reinterpret_cast<const float4*>(a2d + w * 16 + g * 4);
  float ps = acc2[0] * avs.x + acc2[1] * avs.y + acc2[2] * avs.z + acc2[3] * avs.w;
  float pd = acc2[0] * avd.x + acc2[1] * avd.y + acc2[2] * avd.z + acc2[3] * avd.w;
  ushort4 hb;
  hb.x = f2bf(acc2[0]); hb.y = f2bf(acc2[1]);
  hb.z = f2bf(acc2[2]); hb.w = f2bf(acc2[3]);
  *reinterpret_cast<ushort4*>(h2 + (size_t)(n0 + r16) * HID + w * 16 + g * 4) = hb;
  ps += __shfl_xor(ps, 16, 64);
  ps += __shfl_xor(ps, 32, 64);
  pd += __shfl_xor(pd, 16, 64);
  pd += __shfl_xor(pd, 32, 64);
  if (g == 0) { pbuf_s[w][r16] = ps; pbuf_d[w][r16] = pd; }
  __syncthreads();
  if (w == 0 && g == 0) {
    const float pst = pbuf_s[0][r16] + pbuf_s[1][r16] + pbuf_s[2][r16] + pbuf_s[3][r16];
    const float pdt = pbuf_d[0][r16] + pbuf_d[1][r16] + pbuf_d[2][r16] + pbuf_d[3][r16];
    als2[n0 + r16] = pst * LOG2E;
    ald2[n0 + r16] = pdt * LOG2E;
  }
}

// ---------------- layer-2 aggregation v3: group-per-node + 2-deep pipelined gather ----------------

__global__ __launch_bounds__(256) void msg2_fused(
    const int* __restrict__ rowptr, const int* __restrict__ csr,
    const float* __restrict__ als2, const float* __restrict__ ald2,
    const bf16_t* __restrict__ h2, const float* __restrict__ b2,
    float* __restrict__ out, int Nn) {
  const int wid = threadIdx.x >> 6;
  const int lane = threadIdx.x & 63;
  const int l16 = lane & 15;
  const int epar = l16 >> 3;
  const int sub8 = l16 & 7;
  int d = (blockIdx.x * 4 + wid) * 4 + (lane >> 4);
  const bool dvalid = d < Nn;
  if (!dvalid) d = Nn - 1;
  const int r0 = rowptr[d], r1 = rowptr[d + 1];
  const float aldd = ald2[d];

  float acc[8];
#pragma unroll
  for (int f = 0; f < 8; ++f) acc[f] = 0.f;
  float ws = 0.f;

  const int base = (lane & 48) + epar;
  int cb = r0;
  int maxrem = r1 - cb;
  maxrem = max(maxrem, __shfl_xor(maxrem, 16, 64));
  maxrem = max(maxrem, __shfl_xor(maxrem, 32, 64));

#define M2_STEP_FMA(HV, WJ) {                                                       \
    acc[0] += WJ * __uint_as_float(HV.x << 16);                                     \
    acc[1] += WJ * __uint_as_float(HV.x & 0xffff0000u);                             \
    acc[2] += WJ * __uint_as_float(HV.y << 16);                                     \
    acc[3] += WJ * __uint_as_float(HV.y & 0xffff0000u);                             \
    acc[4] += WJ * __uint_as_float(HV.z << 16);                                     \
    acc[5] += WJ * __uint_as_float(HV.z & 0xffff0000u);                             \
    acc[6] += WJ * __uint_as_float(HV.w << 16);                                     \
    acc[7] += WJ * __uint_as_float(HV.w & 0xffff0000u);                             \
  }

  while (maxrem > 0) {
    const int eown = cb + l16;
    const int s_ = csr[min(eown, r1 - 1)];
    float sc = als2[s_] + aldd;
    sc = fmaxf(sc, 0.2f * sc);
    float w = exp2f(sc);
    if (eown >= r1) w = 0.f;
    ws += w;
    const int nstep = (min(16, maxrem) + 1) >> 1;
    int t = 0;
    for (; t + 2 <= nstep; t += 2) {
      const int idxA = base + 2 * t;
      const int idxB = idxA + 2;
      const int sjA = __shfl(s_, idxA, 64);
      const int sjB = __shfl(s_, idxB, 64);
      const uint4 hvA = *reinterpret_cast<const uint4*>(h2 + (size_t)sjA * HID + 8 * sub8);
      const uint4 hvB = *reinterpret_cast<const uint4*>(h2 + (size_t)sjB * HID + 8 * sub8);
      const float wA = __shfl(w, idxA, 64);
      const float wB = __shfl(w, idxB, 64);
      M2_STEP_FMA(hvA, wA)
      M2_STEP_FMA(hvB, wB)
    }
    if (t < nstep) {
      const int idxA = base + 2 * t;
      const int sjA = __shfl(s_, idxA, 64);
      const uint4 hvA = *reinterpret_cast<const uint4*>(h2 + (size_t)sjA * HID + 8 * sub8);
      const float wA = __shfl(w, idxA, 64);
      M2_STEP_FMA(hvA, wA)
    }
    cb += 16;
    maxrem = r1 - cb;
    maxrem = max(maxrem, __shfl_xor(maxrem, 16, 64));
    maxrem = max(maxrem, __shfl_xor(maxrem, 32, 64));
  }

#pragma unroll
  for (int off = 1; off < 16; off <<= 1) ws += __shfl_xor(ws, off, 64);
#pragma unroll
  for (int f = 0; f < 8; ++f) acc[f] += __shfl_xor(acc[f], 8, 64);

  if (dvalid) {
    const float inv = 1.f / (ws + 1e-16f);
    const int fo = 8 * sub8 + 4 * epar;
    const float4 bb = *reinterpret_cast<const float4*>(b2 + fo);
    float4 o;
    o.x = (epar ? acc[4] : acc[0]) * inv + bb.x;
    o.y = (epar ? acc[5] : acc[1]) * inv + bb.y;
    o.z = (epar ? acc[6] : acc[2]) * inv + bb.z;
    o.w = (epar ? acc[7] : acc[3]) * inv + bb.w;
    *reinterpret_cast<float4*>(out + (size_t)d * HID + fo) = o;
  }
}

// ---------------- fused pool + classifier (4 waves/graph, unrolled MLP) ----------------

__device__ inline int lbound(const int* __restrict__ a, int n, int v) {
  int lo = 0, hi = n;
  while (lo < hi) { int m = (lo + hi) >> 1; if (a[m] < v) lo = m + 1; else hi = m; }
  return lo;
}

__global__ __launch_bounds__(256) void pool_cls_kernel(
    const float* __restrict__ out2, const int* __restrict__ batch,
    const float* __restrict__ Wc, const float* __restrict__ bc,
    float* __restrict__ out, int Nn, int C) {
  __shared__ float part[4][HID];
  __shared__ float es[HID];
  const int g = blockIdx.x;
  const int w = threadIdx.x >> 6;      // wave id: node-range slice
  const int t = threadIdx.x & 63;      // feature
  const int lo = lbound(batch, Nn, g);
  const int hi = lbound(batch, Nn, g + 1);
  float acc0 = 0.f, acc1 = 0.f, acc2 = 0.f, acc3 = 0.f;
  int n = lo + w;
  for (; n + 12 < hi; n += 16) {
    acc0 += out2[(size_t)(n) * HID + t];
    acc1 += out2[(size_t)(n + 4) * HID + t];
    acc2 += out2[(size_t)(n + 8) * HID + t];
    acc3 += out2[(size_t)(n + 12) * HID + t];
  }
  for (; n < hi; n += 4) acc0 += out2[(size_t)n * HID + t];
  part[w][t] = (acc0 + acc1) + (acc2 + acc3);
  __syncthreads();
  if (w == 0) {
    const int cnt = hi - lo;
    const float cf = (float)(cnt > 1 ? cnt : 1);
    es[t] = (part[0][t] + part[1][t] + part[2][t] + part[3][t]) / cf;
  }
  __syncthreads();
  for (int c = threadIdx.x; c < C; c += 256) {
    float a = bc[c];
#pragma unroll
    for (int d = 0; d < HID; ++d) a += es[d] * Wc[d * C + c];
    out[g * C + c] = a;
  }
}

extern "C" void kernel_launch(void* const* d_in, const int* in_sizes, int n_in,
                              void* d_out, int out_size, void* d_ws, size_t ws_size,
                              hipStream_t stream) {
  const float* x      = (const float*)d_in[0];
  const float* W1     = (const float*)d_in[1];
  const float* a_src1 = (const float*)d_in[2];
  const float* a_dst1 = (const float*)d_in[3];
  const float* b1     = (const float*)d_in[4];
  const float* W2     = (const float*)d_in[5];
  const float* a_src2 = (const float*)d_in[6];
  const float* a_dst2 = (const float*)d_in[7];
  const float* b2     = (const float*)d_in[8];
  const float* Wc     = (const float*)d_in[9];
  const float* bc     = (const float*)d_in[10];
  const int*   ei     = (const int*)d_in[11];
  const int*   batch  = (const int*)d_in[12];

  const int N = in_sizes[0] / HID;   // 50000
  const int E = in_sizes[11] / 2;    // 800000
  const int C = in_sizes[10];        // 120
  const int Etot = E + N;
  const int nbuck = (N + 255) >> 8;  // 196

  // workspace layout (all regions 16B-aligned)
  bf16_t* AGG = (bf16_t*)d_ws;                          // N*256 bf16; OUT2 f32 overlay later
  bf16_t* XBF = AGG + (size_t)N * C1;                   // N*64 bf16 -> h2 overlay
  float4* ALS1 = (float4*)(XBF + (size_t)N * HID);      // N float4 (scaled)
  float4* ALD1 = ALS1 + N;                              // N float4
  float* ALS2 = (float*)(ALD1 + N);                     // N f32 (scaled)
  float* ALD2 = ALS2 + N;                               // N f32
  int* ROWP   = (int*)(ALD2 + N);                       // N+4 (padded)
  int* BCNT   = ROWP + (N + 4);                         // 256
  int* CSR    = BCNT + 256;                             // Etot
  unsigned* EBUF = (unsigned*)(CSR + Etot);             // 256*BCAP
  float* VA   = (float*)(EBUF + 256 * BCAP);            // 512
  bf16_t* W1T = (bf16_t*)(VA + 512);                    // 16384 bf16
  bf16_t* W2T = W1T + 16384;                            // 16384 bf16

  bf16_t* H2B = XBF;                     // overlay (x_bf dead after msg1_agg)
  float* OUT2 = (float*)AGG;             // overlay (agg dead after gemm12_mfma)

  // ---- constants + BCNT zero (replaces memset dispatch) ----
  const_prep<<<64, 256, 0, stream>>>(W1, a_src1, a_dst1, W2, VA, W1T, W2T, BCNT);

  // ---- CSR build (bucket counting sort, all scatter in LDS) ----
  bin_kernel<<<(Etot + BIN_CHUNK - 1) / BIN_CHUNK, 256, 0, stream>>>(ei, BCNT, EBUF, E, N, nbuck);
  csr_kernel<<<nbuck, 256, 0, stream>>>(BCNT, EBUF, CSR, ROWP, N, nbuck);

  // ---- layer 1 ----
  prep_kernel<<<(N + 15) / 16, 256, 0, stream>>>(x, VA, XBF, ALS1, ALD1, N);
  msg1_agg<<<(N + 15) / 16, 256, 0, stream>>>(ROWP, CSR, ALS1, ALD1, XBF, AGG, N);

  // ---- fused dense chain on MFMA: agg -> x2 (LDS) -> h2, score scalars ----
  gemm12_mfma<<<(N + 15) / 16, 256, 0, stream>>>(AGG, W1T, b1, W2T, a_src2, a_dst2,
                                                 H2B, ALS2, ALD2, N);

  // ---- layer 2 aggregation ----
  msg2_fused<<<(N + 15) / 16, 256, 0, stream>>>(ROWP, CSR, ALS2, ALD2, H2B, b2, OUT2, N);

  // ---- pool + classifier ----
  pool_cls_kernel<<<NGRAPH, 256, 0, stream>>>(OUT2, batch, Wc, bc, (float*)d_out, N, C);
}